// Round 10
// baseline (903.542 us; speedup 1.0000x reference)
//
#include <hip/hip_runtime.h>
#include <math.h>

// SimplePlayerModel on MI355X — Round 10.
// R9 analysis: main GEMM is LDS-BW-bound — every wave reads ALL 256 W-cols
// from LDS (32 ds_read_b128/kt ~384 cyc vs 230 MFMA cyc). Fix: col-split
// waves (wave = 64 rows x 64 cols -> 8 ds_read/kt) + W still LDS-staged via
// the R7-proven async global_load_lds double-buffer. LN via cross-wave LDS
// reduce. Attention, tail, reduce: unchanged from R9 (best: 773us).

typedef __bf16 bf16x8 __attribute__((ext_vector_type(8)));
typedef __bf16 bf16x4 __attribute__((ext_vector_type(4)));
typedef __bf16 bf16x2 __attribute__((ext_vector_type(2)));
typedef float  f32x4  __attribute__((ext_vector_type(4)));
typedef unsigned short u16;
typedef unsigned short u16x8 __attribute__((ext_vector_type(8)));

typedef __attribute__((address_space(1))) const unsigned char gas_char;
typedef __attribute__((address_space(3))) unsigned char las_char;
#define GLL16(g, l) __builtin_amdgcn_global_load_lds((gas_char*)(g), (las_char*)(l), 16, 0, 0)

__device__ __forceinline__ u16 f2b(float f) {            // fp32 -> bf16 RNE
    unsigned int u = __builtin_bit_cast(unsigned int, f);
    return (u16)((u + 0x7fffu + ((u >> 16) & 1u)) >> 16);
}
__device__ __forceinline__ float b2f(u16 u) {
    unsigned int v = ((unsigned int)u) << 16;
    return __builtin_bit_cast(float, v);
}
__device__ __forceinline__ bf16x8 ld2x64(const u16* p) { // two 8B LDS loads
    bf16x4 lo = *(const bf16x4*)p;
    bf16x4 hi = *(const bf16x4*)(p + 4);
    return __builtin_shufflevector(lo, hi, 0, 1, 2, 3, 4, 5, 6, 7);
}
__device__ __forceinline__ bf16x8 ld4x32(const u16* p) { // four 4B LDS loads
    bf16x2 a = *(const bf16x2*)p,     b = *(const bf16x2*)(p + 2);
    bf16x2 c = *(const bf16x2*)(p + 4), d = *(const bf16x2*)(p + 6);
    bf16x4 lo = __builtin_shufflevector(a, b, 0, 1, 2, 3);
    bf16x4 hi = __builtin_shufflevector(c, d, 0, 1, 2, 3);
    return __builtin_shufflevector(lo, hi, 0, 1, 2, 3, 4, 5, 6, 7);
}
__device__ __forceinline__ void split8(const float* __restrict__ s,
                                       bf16x8& hi, bf16x8& lo) {
    u16x8 h, l;
    #pragma unroll
    for (int j = 0; j < 8; ++j) {
        float v  = s[j];
        u16  hb  = f2b(v);
        h[j] = hb;
        l[j] = f2b(v - b2f(hb));
    }
    hi = __builtin_bit_cast(bf16x8, h);
    lo = __builtin_bit_cast(bf16x8, l);
}

// ---------------------------------- col-split, LDS-staged bf16x3 MFMA GEMM
// Block = 256 thr, 64 rows x 256 cols. Wave wv: ALL 64 rows (rt=0..3) x cols
// [wv*64, wv*64+64) (nt=0..3) -> only 8 ds_read_b128 per kt per wave.
// W (hi+lo) double-buffered in LDS via async global_load_lds; A ring-3
// prefetch (2 kt ahead). LN: cross-wave LDS reduce.
template<int IN, bool LN, bool RES, bool AF32, int OMODE>
__device__ __forceinline__
void gemm_body(const void* __restrict__ Xa, const void* __restrict__ Xb, int ldX,
               const u16* __restrict__ Whi, const u16* __restrict__ Wlo,
               const float* __restrict__ bias,
               const float* __restrict__ g, const float* __restrict__ beta,
               const u16* __restrict__ resh, const u16* __restrict__ resl,
               int ldRes, void* __restrict__ Y0, void* __restrict__ Y1, int ldY,
               u16* __restrict__ Wb)
{
    constexpr int KT = IN / 32;
    const int tid = threadIdx.x;
    const int wv = tid >> 6, lane = tid & 63;
    const int quad = lane >> 4, l16 = lane & 15;
    const long rowblk = (long)blockIdx.x * 64;
    const int colbase = wv * 64;

    __shared__ float r1[4][64], r2[4][64];

    // staging map: chunk cid = tid + i*256 -> LDS byte cid*16 (lane-linear)
    // cid = plane*1024 + nt*64 + slot, slot = q*16 + c
    const u16* sbase[8];
    #pragma unroll
    for (int i = 0; i < 8; ++i) {
        int cid = tid + i * 256;
        int plane = cid >> 10, nt = (cid >> 6) & 15, slot = cid & 63;
        int q = slot >> 4, c = slot & 15;
        sbase[i] = (plane ? Wlo : Whi) + (long)(nt * 16 + c) * IN + q * 8;
    }
    auto stageW = [&](int kt, int buf) {
        #pragma unroll
        for (int i = 0; i < 8; ++i)
            GLL16(sbase[i] + kt * 32,
                  (unsigned char*)Wb + buf * 32768 + (tid + i * 256) * 16);
    };

    bf16x8 ah[3][4], al[3][4];             // A ring-3, 4 row-tiles each
    auto loadA = [&](int kt) {
        int s = kt % 3;
        #pragma unroll
        for (int rt = 0; rt < 4; ++rt) {
            long aofs = (rowblk + rt * 16 + l16) * (long)ldX + kt * 32 + quad * 8;
            if constexpr (AF32) {
                float av[8];
                *(f32x4*)&av[0] = *(const f32x4*)&((const float*)Xa)[aofs];
                *(f32x4*)&av[4] = *(const f32x4*)&((const float*)Xa)[aofs + 4];
                split8(av, ah[s][rt], al[s][rt]);
            } else {
                ah[s][rt] = *(const bf16x8*)&((const u16*)Xa)[aofs];
                al[s][rt] = *(const bf16x8*)&((const u16*)Xb)[aofs];
            }
        }
    };

    f32x4 acc[4][4];   // [nt][rt]
    #pragma unroll
    for (int nt = 0; nt < 4; ++nt)
        #pragma unroll
        for (int rt = 0; rt < 4; ++rt) acc[nt][rt] = f32x4{0.f, 0.f, 0.f, 0.f};

    stageW(0, 0);
    if (KT > 1) stageW(1, 1);
    loadA(0);
    if (KT > 1) loadA(1);
    __syncthreads();

    #pragma unroll
    for (int kt = 0; kt < KT; ++kt) {
        if (kt + 2 < KT) loadA(kt + 2);
        const u16* wb = Wb + (kt & 1) * 16384;
        const int s = kt % 3;
        #pragma unroll
        for (int nt = 0; nt < 4; ++nt) {
            const int ntg = wv * 4 + nt;
            bf16x8 bhi = *(const bf16x8*)&wb[ntg * 512 + lane * 8];
            bf16x8 blo = *(const bf16x8*)&wb[(16 + ntg) * 512 + lane * 8];
            #pragma unroll
            for (int rt = 0; rt < 4; ++rt) {
                acc[nt][rt] = __builtin_amdgcn_mfma_f32_16x16x32_bf16(al[s][rt], bhi, acc[nt][rt], 0, 0, 0);
                acc[nt][rt] = __builtin_amdgcn_mfma_f32_16x16x32_bf16(ah[s][rt], blo, acc[nt][rt], 0, 0, 0);
                acc[nt][rt] = __builtin_amdgcn_mfma_f32_16x16x32_bf16(ah[s][rt], bhi, acc[nt][rt], 0, 0, 0);
            }
        }
        if (kt + 1 < KT) {
            __syncthreads();
            if (kt + 2 < KT) stageW(kt + 2, kt & 1);
        }
    }

    // bias before LN stats
    #pragma unroll
    for (int nt = 0; nt < 4; ++nt) {
        float bc = bias[colbase + nt * 16 + l16];
        #pragma unroll
        for (int rt = 0; rt < 4; ++rt)
            #pragma unroll
            for (int r = 0; r < 4; ++r) acc[nt][rt][r] += bc;
    }

    float mean[4][4], rstd[4][4];   // [rt][r]
    if constexpr (LN) {
        float s1[4][4], s2[4][4];
        #pragma unroll
        for (int rt = 0; rt < 4; ++rt)
            #pragma unroll
            for (int r = 0; r < 4; ++r) { s1[rt][r] = 0.f; s2[rt][r] = 0.f; }
        #pragma unroll
        for (int nt = 0; nt < 4; ++nt)
            #pragma unroll
            for (int rt = 0; rt < 4; ++rt)
                #pragma unroll
                for (int r = 0; r < 4; ++r) {
                    s1[rt][r] += acc[nt][rt][r];
                    s2[rt][r] += acc[nt][rt][r] * acc[nt][rt][r];
                }
        #pragma unroll
        for (int off = 1; off < 16; off <<= 1)
            #pragma unroll
            for (int rt = 0; rt < 4; ++rt)
                #pragma unroll
                for (int r = 0; r < 4; ++r) {
                    s1[rt][r] += __shfl_xor(s1[rt][r], off, 64);
                    s2[rt][r] += __shfl_xor(s2[rt][r], off, 64);
                }
        __syncthreads();               // Wb double-buffer no longer needed
        if (l16 == 0) {
            #pragma unroll
            for (int rt = 0; rt < 4; ++rt)
                #pragma unroll
                for (int r = 0; r < 4; ++r) {
                    r1[wv][rt * 16 + quad * 4 + r] = s1[rt][r];
                    r2[wv][rt * 16 + quad * 4 + r] = s2[rt][r];
                }
        }
        __syncthreads();
        #pragma unroll
        for (int rt = 0; rt < 4; ++rt)
            #pragma unroll
            for (int r = 0; r < 4; ++r) {
                int row = rt * 16 + quad * 4 + r;
                float t1 = r1[0][row] + r1[1][row] + r1[2][row] + r1[3][row];
                float t2 = r2[0][row] + r2[1][row] + r2[2][row] + r2[3][row];
                mean[rt][r] = t1 * (1.0f / 256.f);
                float var = t2 * (1.0f / 256.f) - mean[rt][r] * mean[rt][r];
                rstd[rt][r] = rsqrtf(var + 1e-5f);
            }
    }

    #pragma unroll
    for (int nt = 0; nt < 4; ++nt) {
        int col = colbase + nt * 16 + l16;
        float gc = 1.f, bc2 = 0.f;
        if constexpr (LN) { gc = g[col]; bc2 = beta[col]; }
        #pragma unroll
        for (int rt = 0; rt < 4; ++rt)
            #pragma unroll
            for (int r = 0; r < 4; ++r) {
                long row = rowblk + rt * 16 + quad * 4 + r;
                float v = acc[nt][rt][r];
                if constexpr (LN) v = (v - mean[rt][r]) * rstd[rt][r] * gc + bc2;
                if constexpr (RES)
                    v += b2f(resh[row * ldRes + col]) + b2f(resl[row * ldRes + col]);
                long yofs = row * ldY + col;
                if constexpr (OMODE == 0) {
                    ((float*)Y0)[yofs] = v;
                } else if constexpr (OMODE == 1) {
                    u16 hb = f2b(v);
                    ((u16*)Y0)[yofs] = hb;
                    ((u16*)Y1)[yofs] = f2b(v - b2f(hb));
                } else {
                    ((u16*)Y0)[yofs] = f2b(v);
                }
            }
    }
}

template<int IN, bool LN, bool RES, bool AF32, int OMODE>
__global__ __launch_bounds__(256)
void gemm_kernel(const void* __restrict__ Xa, const void* __restrict__ Xb, int ldX,
                 const u16* __restrict__ Whi, const u16* __restrict__ Wlo,
                 const float* __restrict__ bias,
                 const float* __restrict__ g, const float* __restrict__ beta,
                 const u16* __restrict__ resh, const u16* __restrict__ resl,
                 int ldRes, void* __restrict__ Y0, void* __restrict__ Y1, int ldY)
{
    __shared__ u16 Wb[32768];
    gemm_body<IN, LN, RES, AF32, OMODE>(Xa, Xb, ldX, Whi, Wlo, bias, g,
                                        beta, resh, resl, ldRes, Y0, Y1,
                                        ldY, Wb);
}

// qkv projections: grid.y = wsel in {0,1,2}; plain-bf16 token-major out.
__global__ __launch_bounds__(256)
void qkv_proj(const u16* __restrict__ ph, const u16* __restrict__ pl,
              const u16* __restrict__ cwL, const float* __restrict__ cb,
              u16* __restrict__ qb, u16* __restrict__ kb, u16* __restrict__ vh)
{
    __shared__ u16 Wb[32768];
    int wsel = blockIdx.y;
    const u16* whi = cwL + (long)wsel * 65536;
    const u16* wlo = cwL + 393216 + (long)wsel * 65536;
    u16* Y = (wsel == 0) ? qb : (wsel == 1) ? kb : vh;
    gemm_body<256, false, false, false, 2>(
        ph, pl, 256, whi, wlo, cb + wsel * 256, nullptr, nullptr,
        nullptr, nullptr, 0, Y, nullptr, 256, Wb);
}

// ----------------------------------------------- combined in_proj @ qkv_proj
__global__ __launch_bounds__(256)
void combine_kernel(const float* __restrict__ inw, const float* __restrict__ inb,
                    const float* __restrict__ qw, const float* __restrict__ kw,
                    const float* __restrict__ vw, const float* __restrict__ qb,
                    const float* __restrict__ kb, const float* __restrict__ vb,
                    u16* __restrict__ cw, float* __restrict__ cb)
{
    int idx = blockIdx.y, L = idx / 3, wsel = idx % 3;
    const float* Wa = inw + (long)L * 768 * 256 + wsel * 65536;
    const float* ba = inb + L * 768 + wsel * 256;
    const float* Wf = (wsel == 0 ? qw : wsel == 1 ? kw : vw) + (long)L * 65536;
    const float* bf = (wsel == 0 ? qb : wsel == 1 ? kb : vb) + L * 256;

    int o = blockIdx.x, j = threadIdx.x;
    float s = 0.f;
    for (int mm = 0; mm < 256; ++mm)
        s += Wa[o * 256 + mm] * Wf[mm * 256 + j];
    u16 hb = f2b(s);
    cw[(long)idx * 65536 + o * 256 + j] = hb;
    cw[393216 + (long)idx * 65536 + o * 256 + j] = f2b(s - b2f(hb));

    __shared__ float red[256];
    red[j] = Wa[o * 256 + j] * bf[j];
    __syncthreads();
    for (int st = 128; st > 0; st >>= 1) {
        if (j < st) red[j] += red[j + st];
        __syncthreads();
    }
    if (j == 0) cb[idx * 256 + o] = red[0] + ba[o];
}

// ------------------------------------------- fp32 -> hi/lo bf16 weight planes
__global__ __launch_bounds__(256)
void cast_split_multi(const float* s0, u16* d0, int n0,
                      const float* s1, u16* d1, int n1,
                      const float* s2, u16* d2, int n2,
                      const float* s3, u16* d3, int n3,
                      const float* s4, u16* d4, int n4,
                      const float* s5, u16* d5, int n5)
{
    const float* s; u16* d; int n;
    switch (blockIdx.y) {
        case 0: s = s0; d = d0; n = n0; break;
        case 1: s = s1; d = d1; n = n1; break;
        case 2: s = s2; d = d2; n = n2; break;
        case 3: s = s3; d = d3; n = n3; break;
        case 4: s = s4; d = d4; n = n4; break;
        default: s = s5; d = d5; n = n5; break;
    }
    int i = (blockIdx.x * 256 + threadIdx.x) * 4;
    if (i >= n) return;
    float4 v = *(const float4*)&s[i];
    ushort4 h, l;
    h.x = f2b(v.x); l.x = f2b(v.x - b2f(h.x));
    h.y = f2b(v.y); l.y = f2b(v.y - b2f(h.y));
    h.z = f2b(v.z); l.z = f2b(v.z - b2f(h.z));
    h.w = f2b(v.w); l.w = f2b(v.w - b2f(h.w));
    *(ushort4*)&d[i] = h;
    *(ushort4*)&d[n + i] = l;
}

// ------------------------------------------------------- MFMA flash attention
// (unchanged from R9: no-max softmax, P/V single-plane bf16, in-kernel V
// transpose to LDS)
#define VTS 66
#define PS  68
#define EXP2SCALE 0.18033688089184986f   // 0.125 * log2(e)

__global__ __launch_bounds__(256)
void attn_kernel(const u16* __restrict__ qbuf, const u16* __restrict__ kbuf,
                 const u16* __restrict__ vh,
                 u16* __restrict__ ofh, u16* __restrict__ ofl)
{
    const int n = blockIdx.x, h = blockIdx.y, sq = blockIdx.z;
    const int tid = threadIdx.x;
    const int wv = tid >> 6, lane = tid & 63;
    const int quad = lane >> 4, l16 = lane & 15;

    __shared__ u16 Vth[64 * VTS];
    __shared__ u16 Pbh[4][32 * PS];

    bf16x8 qf[2][2];
    #pragma unroll
    for (int rt = 0; rt < 2; ++rt)
        #pragma unroll
        for (int kc = 0; kc < 2; ++kc) {
            long s = sq * 128 + wv * 32 + rt * 16 + l16;
            qf[rt][kc] = *(const bf16x8*)&qbuf[(s * 64 + n) * 256 + h * 64
                                               + kc * 32 + quad * 8];
        }

    f32x4 o[2][4];
    #pragma unroll
    for (int rt = 0; rt < 2; ++rt)
        #pragma unroll
        for (int dt = 0; dt < 4; ++dt) o[rt][dt] = f32x4{0.f, 0.f, 0.f, 0.f};
    float l_run[2][4] = {{0.f, 0.f, 0.f, 0.f}, {0.f, 0.f, 0.f, 0.f}};

    for (int tb = 0; tb < 8; ++tb) {
        __syncthreads();
        for (int i = tid; i < 512; i += 256) {
            int t = i >> 3, c = i & 7;
            u16x8 hvv = *(const u16x8*)&vh[((long)(tb * 64 + t) * 64 + n) * 256
                                           + h * 64 + c * 8];
            #pragma unroll
            for (int j = 0; j < 8; ++j)
                Vth[(c * 8 + j) * VTS + t] = hvv[j];
        }
        __syncthreads();

        f32x4 sA[2][4];
        #pragma unroll
        for (int rt = 0; rt < 2; ++rt)
            #pragma unroll
            for (int tt = 0; tt < 4; ++tt) sA[rt][tt] = f32x4{0.f, 0.f, 0.f, 0.f};
        #pragma unroll
        for (int kc = 0; kc < 2; ++kc)
            #pragma unroll
            for (int tt = 0; tt < 4; ++tt) {
                bf16x8 kf = *(const bf16x8*)
                    &kbuf[((long)(tb * 64 + tt * 16 + l16) * 64 + n) * 256
                          + h * 64 + kc * 32 + quad * 8];
                sA[0][tt] = __builtin_amdgcn_mfma_f32_16x16x32_bf16(
                    qf[0][kc], kf, sA[0][tt], 0, 0, 0);
                sA[1][tt] = __builtin_amdgcn_mfma_f32_16x16x32_bf16(
                    qf[1][kc], kf, sA[1][tt], 0, 0, 0);
            }

        #pragma unroll
        for (int rt = 0; rt < 2; ++rt)
            #pragma unroll
            for (int r = 0; r < 4; ++r) {
                float p0 = exp2f(sA[rt][0][r] * EXP2SCALE);
                float p1 = exp2f(sA[rt][1][r] * EXP2SCALE);
                float p2 = exp2f(sA[rt][2][r] * EXP2SCALE);
                float p3 = exp2f(sA[rt][3][r] * EXP2SCALE);
                int prow = (rt * 16 + quad * 4 + r) * PS + l16;
                Pbh[wv][prow +  0] = f2b(p0);
                Pbh[wv][prow + 16] = f2b(p1);
                Pbh[wv][prow + 32] = f2b(p2);
                Pbh[wv][prow + 48] = f2b(p3);
                l_run[rt][r] += (p0 + p1) + (p2 + p3);
            }

        #pragma unroll
        for (int kc = 0; kc < 2; ++kc) {
            bf16x8 pfh[2];
            #pragma unroll
            for (int rt = 0; rt < 2; ++rt)
                pfh[rt] = ld2x64(&Pbh[wv][(rt * 16 + l16) * PS
                                          + kc * 32 + quad * 8]);
            #pragma unroll
            for (int dt = 0; dt < 4; ++dt) {
                bf16x8 vfh = ld4x32(&Vth[(dt * 16 + l16) * VTS
                                         + kc * 32 + quad * 8]);
                o[0][dt] = __builtin_amdgcn_mfma_f32_16x16x32_bf16(
                    pfh[0], vfh, o[0][dt], 0, 0, 0);
                o[1][dt] = __builtin_amdgcn_mfma_f32_16x16x32_bf16(
                    pfh[1], vfh, o[1][dt], 0, 0, 0);
            }
        }
    }

    #pragma unroll
    for (int off = 1; off < 16; off <<= 1)
        #pragma unroll
        for (int rt = 0; rt < 2; ++rt)
            #pragma unroll
            for (int r = 0; r < 4; ++r)
                l_run[rt][r] += __shfl_xor(l_run[rt][r], off, 64);

    #pragma unroll
    for (int rt = 0; rt < 2; ++rt)
        #pragma unroll
        for (int r = 0; r < 4; ++r) {
            float inv = 1.0f / l_run[rt][r];
            long s = sq * 128 + wv * 32 + rt * 16 + quad * 4 + r;
            #pragma unroll
            for (int dt = 0; dt < 4; ++dt) {
                long idx = (s * 64 + n) * 256 + h * 64 + dt * 16 + l16;
                float val = o[rt][dt][r] * inv;
                u16 hb = f2b(val);
                ofh[idx] = hb;
                ofl[idx] = f2b(val - b2f(hb));
            }
        }
}

// -------------------------------------------------- masked team segment-sum
__global__ __launch_bounds__(256)
void team_reduce_kernel(const float* __restrict__ x, const u16* __restrict__ ph,
                        const u16* __restrict__ pl, float* __restrict__ teams)
{
    int b = blockIdx.x, d = threadIdx.x;
    float acc = 0.f;
    for (int pp = 0; pp < 64; ++pp) {
        float flag = x[((long)b * 64 + pp) * 64 + 63];
        if (flag == 1.0f) {
            long idx = ((long)b * 64 + pp) * 256 + d;
            acc += b2f(ph[idx]) + b2f(pl[idx]);
        }
    }
    teams[(long)b * 512 + d]       = acc;
    teams[(long)b * 512 + 256 + d] = acc;
}

// ---------------------------------------- tail GEMM (512-row team layers)
template<int IN, int OUT, bool RES>
__global__ __launch_bounds__(256)
void tail_gemm(const float* __restrict__ X,
               const u16* __restrict__ Whi, const u16* __restrict__ Wlo,
               const float* __restrict__ bias,
               const float* __restrict__ g, const float* __restrict__ beta,
               const float* __restrict__ res, float* __restrict__ Y)
{
    constexpr int NTW = OUT / 64;
    constexpr int KT  = IN / 32;
    const int tid = threadIdx.x;
    const int wv = tid >> 6, lane = tid & 63;
    const int quad = lane >> 4, l16 = lane & 15;
    const int row0 = blockIdx.x * 16;
    const int colbase = wv * (OUT / 4);

    f32x4 acc[NTW];
    #pragma unroll
    for (int nt = 0; nt < NTW; ++nt) acc[nt] = f32x4{0.f, 0.f, 0.f, 0.f};

    #pragma unroll
    for (int kt = 0; kt < KT; ++kt) {
        float av[8];
        long aofs = (long)(row0 + l16) * IN + kt * 32 + quad * 8;
        *(f32x4*)&av[0] = *(const f32x4*)&X[aofs];
        *(f32x4*)&av[4] = *(const f32x4*)&X[aofs + 4];
        bf16x8 ah, al;
        split8(av, ah, al);
        #pragma unroll
        for (int nt = 0; nt < NTW; ++nt) {
            long wofs = (long)(colbase + nt * 16 + l16) * IN + kt * 32 + quad * 8;
            bf16x8 bhi = *(const bf16x8*)&Whi[wofs];
            bf16x8 blo = *(const bf16x8*)&Wlo[wofs];
            acc[nt] = __builtin_amdgcn_mfma_f32_16x16x32_bf16(al, bhi, acc[nt], 0, 0, 0);
            acc[nt] = __builtin_amdgcn_mfma_f32_16x16x32_bf16(ah, blo, acc[nt], 0, 0, 0);
            acc[nt] = __builtin_amdgcn_mfma_f32_16x16x32_bf16(ah, bhi, acc[nt], 0, 0, 0);
        }
    }

    #pragma unroll
    for (int nt = 0; nt < NTW; ++nt) {
        float bc = bias[colbase + nt * 16 + l16];
        #pragma unroll
        for (int r = 0; r < 4; ++r) acc[nt][r] += bc;
    }

    float s1[4] = {0, 0, 0, 0}, s2[4] = {0, 0, 0, 0};
    #pragma unroll
    for (int nt = 0; nt < NTW; ++nt)
        #pragma unroll
        for (int r = 0; r < 4; ++r) {
            s1[r] += acc[nt][r];
            s2[r] += acc[nt][r] * acc[nt][r];
        }
    #pragma unroll
    for (int off = 1; off < 16; off <<= 1)
        #pragma unroll
        for (int r = 0; r < 4; ++r) {
            s1[r] += __shfl_xor(s1[r], off, 64);
            s2[r] += __shfl_xor(s2[r], off, 64);
        }
    __shared__ float r1[64], r2[64];
    if (l16 == 0) {
        #pragma unroll
        for (int r = 0; r < 4; ++r) {
            r1[wv * 16 + quad * 4 + r] = s1[r];
            r2[wv * 16 + quad * 4 + r] = s2[r];
        }
    }
    __syncthreads();
    float mean[4], rstd[4];
    #pragma unroll
    for (int r = 0; r < 4; ++r) {
        int rr = quad * 4 + r;
        float t1 = r1[rr] + r1[16 + rr] + r1[32 + rr] + r1[48 + rr];
        float t2 = r2[rr] + r2[16 + rr] + r2[32 + rr] + r2[48 + rr];
        mean[r] = t1 * (1.0f / OUT);
        float var = t2 * (1.0f / OUT) - mean[r] * mean[r];
        rstd[r] = rsqrtf(var + 1e-5f);
    }
    #pragma unroll
    for (int nt = 0; nt < NTW; ++nt) {
        int col = colbase + nt * 16 + l16;
        float gc = g[col], bc2 = beta[col];
        #pragma unroll
        for (int r = 0; r < 4; ++r) {
            int row = row0 + quad * 4 + r;
            float v = (acc[nt][r] - mean[r]) * rstd[r] * gc + bc2;
            if constexpr (RES) v += res[(long)row * OUT + col];
            Y[(long)row * OUT + col] = v;
        }
    }
}

// -------------------------------------------------------- standalone LN (lnf)
__global__ __launch_bounds__(64)
void ln_kernel(const float* __restrict__ X, const float* __restrict__ g,
               const float* __restrict__ b, float* __restrict__ Y)
{
    int row = blockIdx.x, lane = threadIdx.x;
    float4 v = *(const float4*)&X[(long)row * 256 + lane * 4];
    float s1 = v.x + v.y + v.z + v.w;
    float s2 = v.x*v.x + v.y*v.y + v.z*v.z + v.w*v.w;
    #pragma unroll
    for (int off = 32; off > 0; off >>= 1) {
        s1 += __shfl_xor(s1, off, 64);
        s2 += __shfl_xor(s2, off, 64);
    }
    float mean = s1 * (1.f / 256.f);
    float rstd = rsqrtf(s2 * (1.f / 256.f) - mean * mean + 1e-5f);
    float4 gg = *(const float4*)&g[lane * 4];
    float4 bb = *(const float4*)&b[lane * 4];
    float4 o;
    o.x = (v.x - mean) * rstd * gg.x + bb.x;
    o.y = (v.y - mean) * rstd * gg.y + bb.y;
    o.z = (v.z - mean) * rstd * gg.z + bb.z;
    o.w = (v.w - mean) * rstd * gg.w + bb.w;
    *(float4*)&Y[(long)row * 256 + lane * 4] = o;
}

// ------------------------------------------------------------- final predict
__global__ __launch_bounds__(64)
void pred_kernel(const float* __restrict__ X, const float* __restrict__ pw,
                 const float* __restrict__ pb, float* __restrict__ out)
{
    int row = blockIdx.x, lane = threadIdx.x;
    float4 v = *(const float4*)&X[(long)row * 256 + lane * 4];
    float4 w = *(const float4*)&pw[lane * 4];
    float s = v.x*w.x + v.y*w.y + v.z*w.z + v.w*w.w;
    #pragma unroll
    for (int off = 32; off > 0; off >>= 1) s += __shfl_xor(s, off, 64);
    if (lane == 0) out[row] = s + pb[0];
}

// =========================================================================
extern "C" void kernel_launch(void* const* d_in, const int* in_sizes, int n_in,
                              void* d_out, int out_size, void* d_ws, size_t ws_size,
                              hipStream_t stream)
{
    const float* x         = (const float*)d_in[0];
    const float* emb_w     = (const float*)d_in[1];
    const float* emb_b     = (const float*)d_in[2];
    const float* emb_g     = (const float*)d_in[3];
    const float* emb_beta  = (const float*)d_in[4];
    const float* post_w    = (const float*)d_in[5];
    const float* post_b    = (const float*)d_in[6];
    const float* post_g    = (const float*)d_in[7];
    const float* post_beta = (const float*)d_in[8];
    const float* attn_qw   = (const float*)d_in[9];
    const float* attn_qb   = (const float*)d_in[10];
    const float* attn_kw   = (const float*)d_in[11];
    const float* attn_kb   = (const float*)d_in[12];
    const float* attn_vw   = (const float*)d_in[13];
    const float* attn_vb   = (const float*)d_in[14];
    const float* attn_inw  = (const float*)d_in[15];
    const float* attn_inb  = (const float*)d_in[16];
    const float* attn_outw = (const float*)d_in[17];
    const float* attn_outb = (const float*)d_in[18];
    const float* attn_g    = (const float*)d_in[19];
    const float* attn_beta = (const float*)d_in[20];
    const float* player_w  = (const float*)d_in[21];
    const float* player_b  = (const float*)d_in[22];
    const float* player_g  = (const float*)d_in[23];
    const float* player_bt = (const float*)d_in[24];
    const float* team_w    = (const float*)d_in[25];
    const float* team_b    = (const float*)d_in[26];
    const float* team_g    = (const float*)d_in[27];
    const float* team_beta = (const float*)d_in[28];
    const float* pre_w     = (const float*)d_in[29];
    const float* pre_b     = (const float*)d_in[30];
    const float* pre_g     = (const float*)d_in[31];
    const float* pre_beta  = (const float*)d_in[32];
    const float* lnf_g     = (const float*)d_in[33];
    const float* lnf_b     = (const float*)d_in[34];
    const float* pred_w    = (const float*)d_in[35];
    const float* pred_b    = (const float*)d_in[36];

    // ---- workspace layout
    char* base = (char*)d_ws;
    const size_t NR = (size_t)32768 * 256;
    u16* ph  = (u16*)base;  base += NR * 2;
    u16* pl  = (u16*)base;  base += NR * 2;
    u16* ofh = (u16*)base;  base += NR * 2;
    u16* ofl = (u16*)base;  base += NR * 2;
    u16* vh  = (u16*)base;  base += NR * 2;
    u16* qb  = (u16*)base;  base += NR * 2;
    u16* kb  = (u16*)base;  base += NR * 2;
    float* teams0 = (float*)base; base += (size_t)512 * 512 * 4;
    float* teams1 = (float*)base; base += (size_t)512 * 512 * 4;
    float* o5     = (float*)base; base += (size_t)512 * 256 * 4;
    u16* emb_wp    = (u16*)base;  base += (size_t)2 * 16384 * 2;
    u16* post_wp   = (u16*)base;  base += (size_t)2 * 65536 * 2;
    u16* outw_p    = (u16*)base;  base += (size_t)2 * 131072 * 2;
    u16* player_wp = (u16*)base;  base += (size_t)2 * 131072 * 2;
    u16* team_wp   = (u16*)base;  base += (size_t)2 * 524288 * 2;
    u16* pre_wp    = (u16*)base;  base += (size_t)2 * 131072 * 2;
    u16* cwb       = (u16*)base;  base += (size_t)2 * 393216 * 2;
    float* cbf     = (float*)base; base += (size_t)1536 * 4;

    // 1) weights -> hi/lo bf16 planes
    cast_split_multi<<<dim3(512, 6), 256, 0, stream>>>(
        emb_w, emb_wp, 16384,
        post_w, post_wp, 65536,
        attn_outw, outw_p, 131072,
        player_w, player_wp, 131072,
        team_w, team_wp, 524288,
        pre_w, pre_wp, 131072);

    // 2) combined qkv weights
    combine_kernel<<<dim3(256, 6), 256, 0, stream>>>(
        attn_inw, attn_inb, attn_qw, attn_kw, attn_vw,
        attn_qb, attn_kb, attn_vb, cwb, cbf);

    // 3) embedding + post-embedding
    gemm_kernel<64, true, false, true, 1><<<512, 256, 0, stream>>>(
        x, nullptr, 64, emb_wp, emb_wp + 16384, emb_b, emb_g, emb_beta,
        nullptr, nullptr, 0, ph, pl, 256);
    gemm_kernel<256, true, true, false, 1><<<512, 256, 0, stream>>>(
        ph, pl, 256, post_wp, post_wp + 65536, post_b, post_g, post_beta,
        ph, pl, 256, ph, pl, 256);

    // 4) attention layers
    for (int L = 0; L < 2; ++L) {
        qkv_proj<<<dim3(512, 3), 256, 0, stream>>>(
            ph, pl, cwb + (size_t)L * 3 * 65536, cbf + L * 768, qb, kb, vh);
        attn_kernel<<<dim3(64, 4, 4), 256, 0, stream>>>(qb, kb, vh, ofh, ofl);
        gemm_kernel<256, true, true, false, 1><<<512, 256, 0, stream>>>(
            ofh, ofl, 256, outw_p + (size_t)L * 65536,
            outw_p + 131072 + (size_t)L * 65536, attn_outb + L * 256,
            attn_g + L * 256, attn_beta + L * 256, ph, pl, 256, ph, pl, 256);
    }

    // 5) player layers
    for (int L = 0; L < 2; ++L)
        gemm_kernel<256, true, true, false, 1><<<512, 256, 0, stream>>>(
            ph, pl, 256, player_wp + (size_t)L * 65536,
            player_wp + 131072 + (size_t)L * 65536, player_b + L * 256,
            player_g + L * 256, player_bt + L * 256, ph, pl, 256, ph, pl, 256);

    // 6) masked segment-sum -> teams0 fp32 [512][512]
    team_reduce_kernel<<<512, 256, 0, stream>>>(x, ph, pl, teams0);

    // 7) team layers (ping-pong)
    tail_gemm<512, 512, true><<<32, 256, 0, stream>>>(
        teams0, team_wp, team_wp + 524288, team_b,
        team_g, team_beta, teams0, teams1);
    tail_gemm<512, 512, true><<<32, 256, 0, stream>>>(
        teams1, team_wp + 262144, team_wp + 524288 + 262144, team_b + 512,
        team_g + 512, team_beta + 512, teams1, teams0);

    // 8) pre (512->256) + lnf + pred
    tail_gemm<512, 256, false><<<32, 256, 0, stream>>>(
        teams0, pre_wp, pre_wp + 131072, pre_b, pre_g, pre_beta,
        nullptr, o5);
    ln_kernel<<<512, 64, 0, stream>>>(o5, lnf_g, lnf_b, o5);
    pred_kernel<<<512, 64, 0, stream>>>(o5, pred_w, pred_b, (float*)d_out);
}

// Round 11
// 827.321 us; speedup vs baseline: 1.0921x; 1.0921x over previous
//
#include <hip/hip_runtime.h>
#include <math.h>

// SimplePlayerModel on MI355X — Round 11.
// R10 post-mortem: col-split fixed LDS-BW (MfmaUtil 9->15) but regressed on
// 4x-redundant latency-exposed global A loads + 96-VGPR A ring. R11 keeps
// col-split AND stages A in LDS (hi/lo, 8KB/kt) + W-hi (16KB/kt) via the
// proven lane-linear global_load_lds double-buffer; W-lo direct-global with
// ring prefetch (L2-hot 128KB). 48KB LDS, 1 barrier/kt, LN scratch aliased
// onto A buffer. Emb (fp32-in) keeps R9 row-split body. Attn/tail = R9.

typedef __bf16 bf16x8 __attribute__((ext_vector_type(8)));
typedef __bf16 bf16x4 __attribute__((ext_vector_type(4)));
typedef __bf16 bf16x2 __attribute__((ext_vector_type(2)));
typedef float  f32x4  __attribute__((ext_vector_type(4)));
typedef unsigned short u16;
typedef unsigned short u16x8 __attribute__((ext_vector_type(8)));

typedef __attribute__((address_space(1))) const unsigned char gas_char;
typedef __attribute__((address_space(3))) unsigned char las_char;
#define GLL16(g, l) __builtin_amdgcn_global_load_lds((gas_char*)(g), (las_char*)(l), 16, 0, 0)

__device__ __forceinline__ u16 f2b(float f) {            // fp32 -> bf16 RNE
    unsigned int u = __builtin_bit_cast(unsigned int, f);
    return (u16)((u + 0x7fffu + ((u >> 16) & 1u)) >> 16);
}
__device__ __forceinline__ float b2f(u16 u) {
    unsigned int v = ((unsigned int)u) << 16;
    return __builtin_bit_cast(float, v);
}
__device__ __forceinline__ bf16x8 ld2x64(const u16* p) { // two 8B LDS loads
    bf16x4 lo = *(const bf16x4*)p;
    bf16x4 hi = *(const bf16x4*)(p + 4);
    return __builtin_shufflevector(lo, hi, 0, 1, 2, 3, 4, 5, 6, 7);
}
__device__ __forceinline__ bf16x8 ld4x32(const u16* p) { // four 4B LDS loads
    bf16x2 a = *(const bf16x2*)p,     b = *(const bf16x2*)(p + 2);
    bf16x2 c = *(const bf16x2*)(p + 4), d = *(const bf16x2*)(p + 6);
    bf16x4 lo = __builtin_shufflevector(a, b, 0, 1, 2, 3);
    bf16x4 hi = __builtin_shufflevector(c, d, 0, 1, 2, 3);
    return __builtin_shufflevector(lo, hi, 0, 1, 2, 3, 4, 5, 6, 7);
}
__device__ __forceinline__ void split8(const float* __restrict__ s,
                                       bf16x8& hi, bf16x8& lo) {
    u16x8 h, l;
    #pragma unroll
    for (int j = 0; j < 8; ++j) {
        float v  = s[j];
        u16  hb  = f2b(v);
        h[j] = hb;
        l[j] = f2b(v - b2f(hb));
    }
    hi = __builtin_bit_cast(bf16x8, h);
    lo = __builtin_bit_cast(bf16x8, l);
}

// ------------------- col-split GEMM, A+Whi LDS-staged, Wlo direct (IN=256)
// Block = 256 thr, 64 rows x 256 cols. Wave wv: ALL 64 rows x cols
// [wv*64, wv*64+64). A (hi+lo) + W-hi async-staged to LDS (dbuf, 1 barrier/
// kt); W-lo ring-prefetched from global (L2-hot). LN: cross-wave LDS reduce
// (scratch aliased onto Ab after the K-loop).
template<bool LN, bool RES, int OMODE>
__device__ __forceinline__
void gemm_cs_body(const u16* __restrict__ Xa, const u16* __restrict__ Xb,
                  const u16* __restrict__ Whi, const u16* __restrict__ Wlo,
                  const float* __restrict__ bias,
                  const float* __restrict__ g, const float* __restrict__ beta,
                  const u16* __restrict__ resh, const u16* __restrict__ resl,
                  void* __restrict__ Y0, void* __restrict__ Y1,
                  u16* __restrict__ Wb /*2x8192*/, u16* __restrict__ Ab /*2x4096*/)
{
    constexpr int IN = 256, KT = 8;
    const int tid = threadIdx.x;
    const int wv = tid >> 6, lane = tid & 63;
    const int quad = lane >> 4, l16 = lane & 15;
    const long rowblk = (long)blockIdx.x * 64;
    const int colbase = wv * 64;

    // W-hi staging map: cid = tid + i*256 (i<4); cid = nt16*64 + slot,
    // slot = q*16 + c -> LDS byte cid*16 (lane-linear, GLL16-compatible)
    const u16* sW[4];
    #pragma unroll
    for (int i = 0; i < 4; ++i) {
        int cid = tid + i * 256;
        int nt16 = cid >> 6, slot = cid & 63;
        int q = slot >> 4, c = slot & 15;
        sW[i] = Whi + (long)(nt16 * 16 + c) * IN + q * 8;
    }
    // A staging map: cid = tid + i*256 (i<2); plane=cid>>8, kc=(cid>>6)&3,
    // row=cid&63 -> LDS byte cid*16
    const u16* sA[2];
    #pragma unroll
    for (int i = 0; i < 2; ++i) {
        int cid = tid + i * 256;
        int plane = cid >> 8, kc = (cid >> 6) & 3, row = cid & 63;
        sA[i] = (plane ? Xb : Xa) + (rowblk + row) * IN + kc * 8;
    }
    auto stage = [&](int kt, int buf) {
        #pragma unroll
        for (int i = 0; i < 4; ++i)
            GLL16(sW[i] + kt * 32,
                  (unsigned char*)Wb + buf * 16384 + (tid + i * 256) * 16);
        #pragma unroll
        for (int i = 0; i < 2; ++i)
            GLL16(sA[i] + kt * 32,
                  (unsigned char*)Ab + buf * 8192 + (tid + i * 256) * 16);
    };

    // W-lo ring prefetch (4 frags/kt for this wave's cols)
    bf16x8 blo[2][4];
    auto loadBlo = [&](int kt, int sl) {
        #pragma unroll
        for (int nt = 0; nt < 4; ++nt)
            blo[sl][nt] = *(const bf16x8*)
                &Wlo[(long)(colbase + nt * 16 + l16) * IN + kt * 32 + quad * 8];
    };

    f32x4 acc[4][4];   // [nt][rt]
    #pragma unroll
    for (int nt = 0; nt < 4; ++nt)
        #pragma unroll
        for (int rt = 0; rt < 4; ++rt) acc[nt][rt] = f32x4{0.f, 0.f, 0.f, 0.f};

    stage(0, 0);
    stage(1, 1);
    loadBlo(0, 0);
    loadBlo(1, 1);
    __syncthreads();

    #pragma unroll
    for (int kt = 0; kt < KT; ++kt) {
        const int sl = kt & 1;
        const u16* wb = Wb + sl * 8192;
        const u16* ab = Ab + sl * 4096;
        bf16x8 ah[4], al[4], bhi[4];
        #pragma unroll
        for (int rt = 0; rt < 4; ++rt) {
            ah[rt] = *(const bf16x8*)&ab[(quad * 64 + rt * 16 + l16) * 8];
            al[rt] = *(const bf16x8*)&ab[2048 + (quad * 64 + rt * 16 + l16) * 8];
        }
        #pragma unroll
        for (int nt = 0; nt < 4; ++nt)
            bhi[nt] = *(const bf16x8*)&wb[(wv * 4 + nt) * 512 + lane * 8];
        #pragma unroll
        for (int nt = 0; nt < 4; ++nt)
            #pragma unroll
            for (int rt = 0; rt < 4; ++rt) {
                acc[nt][rt] = __builtin_amdgcn_mfma_f32_16x16x32_bf16(al[rt], bhi[nt], acc[nt][rt], 0, 0, 0);
                acc[nt][rt] = __builtin_amdgcn_mfma_f32_16x16x32_bf16(ah[rt], blo[sl][nt], acc[nt][rt], 0, 0, 0);
                acc[nt][rt] = __builtin_amdgcn_mfma_f32_16x16x32_bf16(ah[rt], bhi[nt], acc[nt][rt], 0, 0, 0);
            }
        if (kt + 1 < KT) {
            __syncthreads();
            if (kt + 2 < KT) { stage(kt + 2, sl); loadBlo(kt + 2, sl); }
        }
    }

    // bias before LN stats
    #pragma unroll
    for (int nt = 0; nt < 4; ++nt) {
        float bc = bias[colbase + nt * 16 + l16];
        #pragma unroll
        for (int rt = 0; rt < 4; ++rt)
            #pragma unroll
            for (int r = 0; r < 4; ++r) acc[nt][rt][r] += bc;
    }

    float mean[4][4], rstd[4][4];   // [rt][r]
    if constexpr (LN) {
        float s1[4][4], s2[4][4];
        #pragma unroll
        for (int rt = 0; rt < 4; ++rt)
            #pragma unroll
            for (int r = 0; r < 4; ++r) { s1[rt][r] = 0.f; s2[rt][r] = 0.f; }
        #pragma unroll
        for (int nt = 0; nt < 4; ++nt)
            #pragma unroll
            for (int rt = 0; rt < 4; ++rt)
                #pragma unroll
                for (int r = 0; r < 4; ++r) {
                    s1[rt][r] += acc[nt][rt][r];
                    s2[rt][r] += acc[nt][rt][r] * acc[nt][rt][r];
                }
        #pragma unroll
        for (int off = 1; off < 16; off <<= 1)
            #pragma unroll
            for (int rt = 0; rt < 4; ++rt)
                #pragma unroll
                for (int r = 0; r < 4; ++r) {
                    s1[rt][r] += __shfl_xor(s1[rt][r], off, 64);
                    s2[rt][r] += __shfl_xor(s2[rt][r], off, 64);
                }
        // LN scratch aliased onto Ab (K-loop done; all staging drained)
        float* r1 = (float*)Ab;          // [4][64]
        float* r2 = r1 + 256;            // [4][64]
        __syncthreads();
        if (l16 == 0) {
            #pragma unroll
            for (int rt = 0; rt < 4; ++rt)
                #pragma unroll
                for (int r = 0; r < 4; ++r) {
                    r1[wv * 64 + rt * 16 + quad * 4 + r] = s1[rt][r];
                    r2[wv * 64 + rt * 16 + quad * 4 + r] = s2[rt][r];
                }
        }
        __syncthreads();
        #pragma unroll
        for (int rt = 0; rt < 4; ++rt)
            #pragma unroll
            for (int r = 0; r < 4; ++r) {
                int row = rt * 16 + quad * 4 + r;
                float t1 = r1[row] + r1[64 + row] + r1[128 + row] + r1[192 + row];
                float t2 = r2[row] + r2[64 + row] + r2[128 + row] + r2[192 + row];
                mean[rt][r] = t1 * (1.0f / 256.f);
                float var = t2 * (1.0f / 256.f) - mean[rt][r] * mean[rt][r];
                rstd[rt][r] = rsqrtf(var + 1e-5f);
            }
    }

    #pragma unroll
    for (int nt = 0; nt < 4; ++nt) {
        int col = colbase + nt * 16 + l16;
        float gc = 1.f, bc2 = 0.f;
        if constexpr (LN) { gc = g[col]; bc2 = beta[col]; }
        #pragma unroll
        for (int rt = 0; rt < 4; ++rt)
            #pragma unroll
            for (int r = 0; r < 4; ++r) {
                long row = rowblk + rt * 16 + quad * 4 + r;
                float v = acc[nt][rt][r];
                if constexpr (LN) v = (v - mean[rt][r]) * rstd[rt][r] * gc + bc2;
                if constexpr (RES)
                    v += b2f(resh[row * 256 + col]) + b2f(resl[row * 256 + col]);
                long yofs = row * 256 + col;
                if constexpr (OMODE == 1) {
                    u16 hb = f2b(v);
                    ((u16*)Y0)[yofs] = hb;
                    ((u16*)Y1)[yofs] = f2b(v - b2f(hb));
                } else {
                    ((u16*)Y0)[yofs] = f2b(v);
                }
            }
    }
}

template<bool LN, bool RES, int OMODE>
__global__ __launch_bounds__(256)
void gemm_cs_kernel(const u16* __restrict__ Xa, const u16* __restrict__ Xb,
                    const u16* __restrict__ Whi, const u16* __restrict__ Wlo,
                    const float* __restrict__ bias,
                    const float* __restrict__ g, const float* __restrict__ beta,
                    const u16* __restrict__ resh, const u16* __restrict__ resl,
                    void* __restrict__ Y0, void* __restrict__ Y1)
{
    __shared__ u16 Wb[2 * 8192];
    __shared__ u16 Ab[2 * 4096];
    gemm_cs_body<LN, RES, OMODE>(Xa, Xb, Whi, Wlo, bias, g, beta,
                                 resh, resl, Y0, Y1, Wb, Ab);
}

// qkv projections: grid.y = wsel in {0,1,2}; plain-bf16 token-major out.
__global__ __launch_bounds__(256)
void qkv_proj(const u16* __restrict__ ph, const u16* __restrict__ pl,
              const u16* __restrict__ cwL, const float* __restrict__ cb,
              u16* __restrict__ qb, u16* __restrict__ kb, u16* __restrict__ vh)
{
    __shared__ u16 Wb[2 * 8192];
    __shared__ u16 Ab[2 * 4096];
    int wsel = blockIdx.y;
    const u16* whi = cwL + (long)wsel * 65536;
    const u16* wlo = cwL + 393216 + (long)wsel * 65536;
    u16* Y = (wsel == 0) ? qb : (wsel == 1) ? kb : vh;
    gemm_cs_body<false, false, 2>(ph, pl, whi, wlo, cb + wsel * 256,
                                  nullptr, nullptr, nullptr, nullptr,
                                  Y, nullptr, Wb, Ab);
}

// --------------------- R9 row-split body, kept for the fp32-input emb layer
__global__ __launch_bounds__(256)
void emb_kernel(const float* __restrict__ X,
                const u16* __restrict__ Whi, const u16* __restrict__ Wlo,
                const float* __restrict__ bias,
                const float* __restrict__ g, const float* __restrict__ beta,
                u16* __restrict__ Y0, u16* __restrict__ Y1)
{
    constexpr int IN = 64, KT = 2;
    __shared__ u16 Wb[32768];
    const int tid = threadIdx.x;
    const int wv = tid >> 6, lane = tid & 63;
    const int quad = lane >> 4, l16 = lane & 15;
    const long arow = (long)blockIdx.x * 64 + wv * 16 + l16;

    const u16* sbase[8];
    int sdst[8];
    #pragma unroll
    for (int i = 0; i < 8; ++i) {
        int cid = tid + i * 256;
        int plane = cid >> 10, nt = (cid >> 6) & 15, slot = cid & 63;
        int q = slot >> 4, c = slot & 15;
        sbase[i] = (plane ? Wlo : Whi) + (long)(nt * 16 + c) * IN + q * 8;
        sdst[i]  = (plane * 16 + nt) * 512 + slot * 8;
    }
    u16x8 wreg[8];
    auto issueW = [&](int kt) {
        #pragma unroll
        for (int i = 0; i < 8; ++i) wreg[i] = *(const u16x8*)(sbase[i] + kt * 32);
    };
    auto commitW = [&](int buf) {
        #pragma unroll
        for (int i = 0; i < 8; ++i)
            *(u16x8*)&Wb[buf * 16384 + sdst[i]] = wreg[i];
    };
    bf16x8 ah[2], al[2];
    auto loadA = [&](int kt) {
        long aofs = arow * IN + kt * 32 + quad * 8;
        float av[8];
        *(f32x4*)&av[0] = *(const f32x4*)&X[aofs];
        *(f32x4*)&av[4] = *(const f32x4*)&X[aofs + 4];
        split8(av, ah[kt & 1], al[kt & 1]);
    };

    f32x4 acc[16];
    #pragma unroll
    for (int nt = 0; nt < 16; ++nt) acc[nt] = f32x4{0.f, 0.f, 0.f, 0.f};

    issueW(0); commitW(0); issueW(1);
    loadA(0); loadA(1);
    __syncthreads();

    #pragma unroll
    for (int kt = 0; kt < KT; ++kt) {
        const u16* wb = Wb + (kt & 1) * 16384;
        const int s = kt & 1;
        #pragma unroll
        for (int nt = 0; nt < 16; ++nt) {
            bf16x8 bhi = *(const bf16x8*)&wb[nt * 512 + lane * 8];
            bf16x8 blo = *(const bf16x8*)&wb[(16 + nt) * 512 + lane * 8];
            acc[nt] = __builtin_amdgcn_mfma_f32_16x16x32_bf16(al[s], bhi, acc[nt], 0, 0, 0);
            acc[nt] = __builtin_amdgcn_mfma_f32_16x16x32_bf16(ah[s], blo, acc[nt], 0, 0, 0);
            acc[nt] = __builtin_amdgcn_mfma_f32_16x16x32_bf16(ah[s], bhi, acc[nt], 0, 0, 0);
        }
        if (kt + 1 < KT) {
            commitW((kt + 1) & 1);
            __syncthreads();
        }
    }

    #pragma unroll
    for (int nt = 0; nt < 16; ++nt) {
        float bc = bias[nt * 16 + l16];
        #pragma unroll
        for (int r = 0; r < 4; ++r) acc[nt][r] += bc;
    }
    float s1[4] = {0, 0, 0, 0}, s2[4] = {0, 0, 0, 0};
    #pragma unroll
    for (int nt = 0; nt < 16; ++nt)
        #pragma unroll
        for (int r = 0; r < 4; ++r) {
            s1[r] += acc[nt][r];
            s2[r] += acc[nt][r] * acc[nt][r];
        }
    #pragma unroll
    for (int off = 1; off < 16; off <<= 1)
        #pragma unroll
        for (int r = 0; r < 4; ++r) {
            s1[r] += __shfl_xor(s1[r], off, 64);
            s2[r] += __shfl_xor(s2[r], off, 64);
        }
    float mean[4], rstd[4];
    #pragma unroll
    for (int r = 0; r < 4; ++r) {
        mean[r] = s1[r] * (1.0f / 256.f);
        float var = s2[r] * (1.0f / 256.f) - mean[r] * mean[r];
        rstd[r] = rsqrtf(var + 1e-5f);
    }
    #pragma unroll
    for (int nt = 0; nt < 16; ++nt) {
        int col = nt * 16 + l16;
        float gc = g[col], bc2 = beta[col];
        #pragma unroll
        for (int r = 0; r < 4; ++r) {
            long row = (long)blockIdx.x * 64 + wv * 16 + quad * 4 + r;
            float v = (acc[nt][r] - mean[r]) * rstd[r] * gc + bc2;
            u16 hb = f2b(v);
            Y0[row * 256 + col] = hb;
            Y1[row * 256 + col] = f2b(v - b2f(hb));
        }
    }
}

// ----------------------------------------------- combined in_proj @ qkv_proj
__global__ __launch_bounds__(256)
void combine_kernel(const float* __restrict__ inw, const float* __restrict__ inb,
                    const float* __restrict__ qw, const float* __restrict__ kw,
                    const float* __restrict__ vw, const float* __restrict__ qb,
                    const float* __restrict__ kb, const float* __restrict__ vb,
                    u16* __restrict__ cw, float* __restrict__ cb)
{
    int idx = blockIdx.y, L = idx / 3, wsel = idx % 3;
    const float* Wa = inw + (long)L * 768 * 256 + wsel * 65536;
    const float* ba = inb + L * 768 + wsel * 256;
    const float* Wf = (wsel == 0 ? qw : wsel == 1 ? kw : vw) + (long)L * 65536;
    const float* bf = (wsel == 0 ? qb : wsel == 1 ? kb : vb) + L * 256;

    int o = blockIdx.x, j = threadIdx.x;
    float s = 0.f;
    for (int mm = 0; mm < 256; ++mm)
        s += Wa[o * 256 + mm] * Wf[mm * 256 + j];
    u16 hb = f2b(s);
    cw[(long)idx * 65536 + o * 256 + j] = hb;
    cw[393216 + (long)idx * 65536 + o * 256 + j] = f2b(s - b2f(hb));

    __shared__ float red[256];
    red[j] = Wa[o * 256 + j] * bf[j];
    __syncthreads();
    for (int st = 128; st > 0; st >>= 1) {
        if (j < st) red[j] += red[j + st];
        __syncthreads();
    }
    if (j == 0) cb[idx * 256 + o] = red[0] + ba[o];
}

// ------------------------------------------- fp32 -> hi/lo bf16 weight planes
__global__ __launch_bounds__(256)
void cast_split_multi(const float* s0, u16* d0, int n0,
                      const float* s1, u16* d1, int n1,
                      const float* s2, u16* d2, int n2,
                      const float* s3, u16* d3, int n3,
                      const float* s4, u16* d4, int n4,
                      const float* s5, u16* d5, int n5)
{
    const float* s; u16* d; int n;
    switch (blockIdx.y) {
        case 0: s = s0; d = d0; n = n0; break;
        case 1: s = s1; d = d1; n = n1; break;
        case 2: s = s2; d = d2; n = n2; break;
        case 3: s = s3; d = d3; n = n3; break;
        case 4: s = s4; d = d4; n = n4; break;
        default: s = s5; d = d5; n = n5; break;
    }
    int i = (blockIdx.x * 256 + threadIdx.x) * 4;
    if (i >= n) return;
    float4 v = *(const float4*)&s[i];
    ushort4 h, l;
    h.x = f2b(v.x); l.x = f2b(v.x - b2f(h.x));
    h.y = f2b(v.y); l.y = f2b(v.y - b2f(h.y));
    h.z = f2b(v.z); l.z = f2b(v.z - b2f(h.z));
    h.w = f2b(v.w); l.w = f2b(v.w - b2f(h.w));
    *(ushort4*)&d[i] = h;
    *(ushort4*)&d[n + i] = l;
}

// ------------------------------------------------------- MFMA flash attention
// (unchanged from R9)
#define VTS 66
#define PS  68
#define EXP2SCALE 0.18033688089184986f   // 0.125 * log2(e)

__global__ __launch_bounds__(256)
void attn_kernel(const u16* __restrict__ qbuf, const u16* __restrict__ kbuf,
                 const u16* __restrict__ vh,
                 u16* __restrict__ ofh, u16* __restrict__ ofl)
{
    const int n = blockIdx.x, h = blockIdx.y, sq = blockIdx.z;
    const int tid = threadIdx.x;
    const int wv = tid >> 6, lane = tid & 63;
    const int quad = lane >> 4, l16 = lane & 15;

    __shared__ u16 Vth[64 * VTS];
    __shared__ u16 Pbh[4][32 * PS];

    bf16x8 qf[2][2];
    #pragma unroll
    for (int rt = 0; rt < 2; ++rt)
        #pragma unroll
        for (int kc = 0; kc < 2; ++kc) {
            long s = sq * 128 + wv * 32 + rt * 16 + l16;
            qf[rt][kc] = *(const bf16x8*)&qbuf[(s * 64 + n) * 256 + h * 64
                                               + kc * 32 + quad * 8];
        }

    f32x4 o[2][4];
    #pragma unroll
    for (int rt = 0; rt < 2; ++rt)
        #pragma unroll
        for (int dt = 0; dt < 4; ++dt) o[rt][dt] = f32x4{0.f, 0.f, 0.f, 0.f};
    float l_run[2][4] = {{0.f, 0.f, 0.f, 0.f}, {0.f, 0.f, 0.f, 0.f}};

    for (int tb = 0; tb < 8; ++tb) {
        __syncthreads();
        for (int i = tid; i < 512; i += 256) {
            int t = i >> 3, c = i & 7;
            u16x8 hvv = *(const u16x8*)&vh[((long)(tb * 64 + t) * 64 + n) * 256
                                           + h * 64 + c * 8];
            #pragma unroll
            for (int j = 0; j < 8; ++j)
                Vth[(c * 8 + j) * VTS + t] = hvv[j];
        }
        __syncthreads();

        f32x4 sA[2][4];
        #pragma unroll
        for (int rt = 0; rt < 2; ++rt)
            #pragma unroll
            for (int tt = 0; tt < 4; ++tt) sA[rt][tt] = f32x4{0.f, 0.f, 0.f, 0.f};
        #pragma unroll
        for (int kc = 0; kc < 2; ++kc)
            #pragma unroll
            for (int tt = 0; tt < 4; ++tt) {
                bf16x8 kf = *(const bf16x8*)
                    &kbuf[((long)(tb * 64 + tt * 16 + l16) * 64 + n) * 256
                          + h * 64 + kc * 32 + quad * 8];
                sA[0][tt] = __builtin_amdgcn_mfma_f32_16x16x32_bf16(
                    qf[0][kc], kf, sA[0][tt], 0, 0, 0);
                sA[1][tt] = __builtin_amdgcn_mfma_f32_16x16x32_bf16(
                    qf[1][kc], kf, sA[1][tt], 0, 0, 0);
            }

        #pragma unroll
        for (int rt = 0; rt < 2; ++rt)
            #pragma unroll
            for (int r = 0; r < 4; ++r) {
                float p0 = exp2f(sA[rt][0][r] * EXP2SCALE);
                float p1 = exp2f(sA[rt][1][r] * EXP2SCALE);
                float p2 = exp2f(sA[rt][2][r] * EXP2SCALE);
                float p3 = exp2f(sA[rt][3][r] * EXP2SCALE);
                int prow = (rt * 16 + quad * 4 + r) * PS + l16;
                Pbh[wv][prow +  0] = f2b(p0);
                Pbh[wv][prow + 16] = f2b(p1);
                Pbh[wv][prow + 32] = f2b(p2);
                Pbh[wv][prow + 48] = f2b(p3);
                l_run[rt][r] += (p0 + p1) + (p2 + p3);
            }

        #pragma unroll
        for (int kc = 0; kc < 2; ++kc) {
            bf16x8 pfh[2];
            #pragma unroll
            for (int rt = 0; rt < 2; ++rt)
                pfh[rt] = ld2x64(&Pbh[wv][(rt * 16 + l16) * PS
                                          + kc * 32 + quad * 8]);
            #pragma unroll
            for (int dt = 0; dt < 4; ++dt) {
                bf16x8 vfh = ld4x32(&Vth[(dt * 16 + l16) * VTS
                                         + kc * 32 + quad * 8]);
                o[0][dt] = __builtin_amdgcn_mfma_f32_16x16x32_bf16(
                    pfh[0], vfh, o[0][dt], 0, 0, 0);
                o[1][dt] = __builtin_amdgcn_mfma_f32_16x16x32_bf16(
                    pfh[1], vfh, o[1][dt], 0, 0, 0);
            }
        }
    }

    #pragma unroll
    for (int off = 1; off < 16; off <<= 1)
        #pragma unroll
        for (int rt = 0; rt < 2; ++rt)
            #pragma unroll
            for (int r = 0; r < 4; ++r)
                l_run[rt][r] += __shfl_xor(l_run[rt][r], off, 64);

    #pragma unroll
    for (int rt = 0; rt < 2; ++rt)
        #pragma unroll
        for (int r = 0; r < 4; ++r) {
            float inv = 1.0f / l_run[rt][r];
            long s = sq * 128 + wv * 32 + rt * 16 + quad * 4 + r;
            #pragma unroll
            for (int dt = 0; dt < 4; ++dt) {
                long idx = (s * 64 + n) * 256 + h * 64 + dt * 16 + l16;
                float val = o[rt][dt][r] * inv;
                u16 hb = f2b(val);
                ofh[idx] = hb;
                ofl[idx] = f2b(val - b2f(hb));
            }
        }
}

// -------------------------------------------------- masked team segment-sum
__global__ __launch_bounds__(256)
void team_reduce_kernel(const float* __restrict__ x, const u16* __restrict__ ph,
                        const u16* __restrict__ pl, float* __restrict__ teams)
{
    int b = blockIdx.x, d = threadIdx.x;
    float acc = 0.f;
    for (int pp = 0; pp < 64; ++pp) {
        float flag = x[((long)b * 64 + pp) * 64 + 63];
        if (flag == 1.0f) {
            long idx = ((long)b * 64 + pp) * 256 + d;
            acc += b2f(ph[idx]) + b2f(pl[idx]);
        }
    }
    teams[(long)b * 512 + d]       = acc;
    teams[(long)b * 512 + 256 + d] = acc;
}

// ---------------------------------------- tail GEMM (512-row team layers)
template<int IN, int OUT, bool RES>
__global__ __launch_bounds__(256)
void tail_gemm(const float* __restrict__ X,
               const u16* __restrict__ Whi, const u16* __restrict__ Wlo,
               const float* __restrict__ bias,
               const float* __restrict__ g, const float* __restrict__ beta,
               const float* __restrict__ res, float* __restrict__ Y)
{
    constexpr int NTW = OUT / 64;
    constexpr int KT  = IN / 32;
    const int tid = threadIdx.x;
    const int wv = tid >> 6, lane = tid & 63;
    const int quad = lane >> 4, l16 = lane & 15;
    const int row0 = blockIdx.x * 16;
    const int colbase = wv * (OUT / 4);

    f32x4 acc[NTW];
    #pragma unroll
    for (int nt = 0; nt < NTW; ++nt) acc[nt] = f32x4{0.f, 0.f, 0.f, 0.f};

    #pragma unroll
    for (int kt = 0; kt < KT; ++kt) {
        float av[8];
        long aofs = (long)(row0 + l16) * IN + kt * 32 + quad * 8;
        *(f32x4*)&av[0] = *(const f32x4*)&X[aofs];
        *(f32x4*)&av[4] = *(const f32x4*)&X[aofs + 4];
        bf16x8 ah, al;
        split8(av, ah, al);
        #pragma unroll
        for (int nt = 0; nt < NTW; ++nt) {
            long wofs = (long)(colbase + nt * 16 + l16) * IN + kt * 32 + quad * 8;
            bf16x8 bhi = *(const bf16x8*)&Whi[wofs];
            bf16x8 blo = *(const bf16x8*)&Wlo[wofs];
            acc[nt] = __builtin_amdgcn_mfma_f32_16x16x32_bf16(al, bhi, acc[nt], 0, 0, 0);
            acc[nt] = __builtin_amdgcn_mfma_f32_16x16x32_bf16(ah, blo, acc[nt], 0, 0, 0);
            acc[nt] = __builtin_amdgcn_mfma_f32_16x16x32_bf16(ah, bhi, acc[nt], 0, 0, 0);
        }
    }

    #pragma unroll
    for (int nt = 0; nt < NTW; ++nt) {
        float bc = bias[colbase + nt * 16 + l16];
        #pragma unroll
        for (int r = 0; r < 4; ++r) acc[nt][r] += bc;
    }

    float s1[4] = {0, 0, 0, 0}, s2[4] = {0, 0, 0, 0};
    #pragma unroll
    for (int nt = 0; nt < NTW; ++nt)
        #pragma unroll
        for (int r = 0; r < 4; ++r) {
            s1[r] += acc[nt][r];
            s2[r] += acc[nt][r] * acc[nt][r];
        }
    #pragma unroll
    for (int off = 1; off < 16; off <<= 1)
        #pragma unroll
        for (int r = 0; r < 4; ++r) {
            s1[r] += __shfl_xor(s1[r], off, 64);
            s2[r] += __shfl_xor(s2[r], off, 64);
        }
    __shared__ float r1[64], r2[64];
    if (l16 == 0) {
        #pragma unroll
        for (int r = 0; r < 4; ++r) {
            r1[wv * 16 + quad * 4 + r] = s1[r];
            r2[wv * 16 + quad * 4 + r] = s2[r];
        }
    }
    __syncthreads();
    float mean[4], rstd[4];
    #pragma unroll
    for (int r = 0; r < 4; ++r) {
        int rr = quad * 4 + r;
        float t1 = r1[rr] + r1[16 + rr] + r1[32 + rr] + r1[48 + rr];
        float t2 = r2[rr] + r2[16 + rr] + r2[32 + rr] + r2[48 + rr];
        mean[r] = t1 * (1.0f / OUT);
        float var = t2 * (1.0f / OUT) - mean[r] * mean[r];
        rstd[r] = rsqrtf(var + 1e-5f);
    }
    #pragma unroll
    for (int nt = 0; nt < NTW; ++nt) {
        int col = colbase + nt * 16 + l16;
        float gc = g[col], bc2 = beta[col];
        #pragma unroll
        for (int r = 0; r < 4; ++r) {
            int row = row0 + quad * 4 + r;
            float v = (acc[nt][r] - mean[r]) * rstd[r] * gc + bc2;
            if constexpr (RES) v += res[(long)row * OUT + col];
            Y[(long)row * OUT + col] = v;
        }
    }
}

// -------------------------------------------------------- standalone LN (lnf)
__global__ __launch_bounds__(64)
void ln_kernel(const float* __restrict__ X, const float* __restrict__ g,
               const float* __restrict__ b, float* __restrict__ Y)
{
    int row = blockIdx.x, lane = threadIdx.x;
    float4 v = *(const float4*)&X[(long)row * 256 + lane * 4];
    float s1 = v.x + v.y + v.z + v.w;
    float s2 = v.x*v.x + v.y*v.y + v.z*v.z + v.w*v.w;
    #pragma unroll
    for (int off = 32; off > 0; off >>= 1) {
        s1 += __shfl_xor(s1, off, 64);
        s2 += __shfl_xor(s2, off, 64);
    }
    float mean = s1 * (1.f / 256.f);
    float rstd = rsqrtf(s2 * (1.f / 256.f) - mean * mean + 1e-5f);
    float4 gg = *(const float4*)&g[lane * 4];
    float4 bb = *(const float4*)&b[lane * 4];
    float4 o;
    o.x = (v.x - mean) * rstd * gg.x + bb.x;
    o.y = (v.y - mean) * rstd * gg.y + bb.y;
    o.z = (v.z - mean) * rstd * gg.z + bb.z;
    o.w = (v.w - mean) * rstd * gg.w + bb.w;
    *(float4*)&Y[(long)row * 256 + lane * 4] = o;
}

// ------------------------------------------------------------- final predict
__global__ __launch_bounds__(64)
void pred_kernel(const float* __restrict__ X, const float* __restrict__ pw,
                 const float* __restrict__ pb, float* __restrict__ out)
{
    int row = blockIdx.x, lane = threadIdx.x;
    float4 v = *(const float4*)&X[(long)row * 256 + lane * 4];
    float4 w = *(const float4*)&pw[lane * 4];
    float s = v.x*w.x + v.y*w.y + v.z*w.z + v.w*w.w;
    #pragma unroll
    for (int off = 32; off > 0; off >>= 1) s += __shfl_xor(s, off, 64);
    if (lane == 0) out[row] = s + pb[0];
}

// =========================================================================
extern "C" void kernel_launch(void* const* d_in, const int* in_sizes, int n_in,
                              void* d_out, int out_size, void* d_ws, size_t ws_size,
                              hipStream_t stream)
{
    const float* x         = (const float*)d_in[0];
    const float* emb_w     = (const float*)d_in[1];
    const float* emb_b     = (const float*)d_in[2];
    const float* emb_g     = (const float*)d_in[3];
    const float* emb_beta  = (const float*)d_in[4];
    const float* post_w    = (const float*)d_in[5];
    const float* post_b    = (const float*)d_in[6];
    const float* post_g    = (const float*)d_in[7];
    const float* post_beta = (const float*)d_in[8];
    const float* attn_qw   = (const float*)d_in[9];
    const float* attn_qb   = (const float*)d_in[10];
    const float* attn_kw   = (const float*)d_in[11];
    const float* attn_kb   = (const float*)d_in[12];
    const float* attn_vw   = (const float*)d_in[13];
    const float* attn_vb   = (const float*)d_in[14];
    const float* attn_inw  = (const float*)d_in[15];
    const float* attn_inb  = (const float*)d_in[16];
    const float* attn_outw = (const float*)d_in[17];
    const float* attn_outb = (const float*)d_in[18];
    const float* attn_g    = (const float*)d_in[19];
    const float* attn_beta = (const float*)d_in[20];
    const float* player_w  = (const float*)d_in[21];
    const float* player_b  = (const float*)d_in[22];
    const float* player_g  = (const float*)d_in[23];
    const float* player_bt = (const float*)d_in[24];
    const float* team_w    = (const float*)d_in[25];
    const float* team_b    = (const float*)d_in[26];
    const float* team_g    = (const float*)d_in[27];
    const float* team_beta = (const float*)d_in[28];
    const float* pre_w     = (const float*)d_in[29];
    const float* pre_b     = (const float*)d_in[30];
    const float* pre_g     = (const float*)d_in[31];
    const float* pre_beta  = (const float*)d_in[32];
    const float* lnf_g     = (const float*)d_in[33];
    const float* lnf_b     = (const float*)d_in[34];
    const float* pred_w    = (const float*)d_in[35];
    const float* pred_b    = (const float*)d_in[36];

    // ---- workspace layout
    char* base = (char*)d_ws;
    const size_t NR = (size_t)32768 * 256;
    u16* ph  = (u16*)base;  base += NR * 2;
    u16* pl  = (u16*)base;  base += NR * 2;
    u16* ofh = (u16*)base;  base += NR * 2;
    u16* ofl = (u16*)base;  base += NR * 2;
    u16* vh  = (u16*)base;  base += NR * 2;
    u16* qb  = (u16*)base;  base += NR * 2;
    u16* kb  = (u16*)base;  base += NR * 2;
    float* teams0 = (float*)base; base += (size_t)512 * 512 * 4;
    float* teams1 = (float*)base; base += (size_t)512 * 512 * 4;
    float* o5     = (float*)base; base += (size_t)512 * 256 * 4;
    u16* emb_wp    = (u16*)base;  base += (size_t)2 * 16384 * 2;
    u16* post_wp   = (u16*)base;  base += (size_t)2 * 65536 * 2;
    u16* outw_p    = (u16*)base;  base += (size_t)2 * 131072 * 2;
    u16* player_wp = (u16*)base;  base += (size_t)2 * 131072 * 2;
    u16* team_wp   = (u16*)base;  base += (size_t)2 * 524288 * 2;
    u16* pre_wp    = (u16*)base;  base += (size_t)2 * 131072 * 2;
    u16* cwb       = (u16*)base;  base += (size_t)2 * 393216 * 2;
    float* cbf     = (float*)base; base += (size_t)1536 * 4;

    // 1) weights -> hi/lo bf16 planes
    cast_split_multi<<<dim3(512, 6), 256, 0, stream>>>(
        emb_w, emb_wp, 16384,
        post_w, post_wp, 65536,
        attn_outw, outw_p, 131072,
        player_w, player_wp, 131072,
        team_w, team_wp, 524288,
        pre_w, pre_wp, 131072);

    // 2) combined qkv weights
    combine_kernel<<<dim3(256, 6), 256, 0, stream>>>(
        attn_inw, attn_inb, attn_qw, attn_kw, attn_vw,
        attn_qb, attn_kb, attn_vb, cwb, cbf);

    // 3) embedding + post-embedding
    emb_kernel<<<512, 256, 0, stream>>>(
        x, emb_wp, emb_wp + 16384, emb_b, emb_g, emb_beta, ph, pl);
    gemm_cs_kernel<true, true, 1><<<512, 256, 0, stream>>>(
        ph, pl, post_wp, post_wp + 65536, post_b, post_g, post_beta,
        ph, pl, ph, pl);

    // 4) attention layers
    for (int L = 0; L < 2; ++L) {
        qkv_proj<<<dim3(512, 3), 256, 0, stream>>>(
            ph, pl, cwb + (size_t)L * 3 * 65536, cbf + L * 768, qb, kb, vh);
        attn_kernel<<<dim3(64, 4, 4), 256, 0, stream>>>(qb, kb, vh, ofh, ofl);
        gemm_cs_kernel<true, true, 1><<<512, 256, 0, stream>>>(
            ofh, ofl, outw_p + (size_t)L * 65536,
            outw_p + 131072 + (size_t)L * 65536, attn_outb + L * 256,
            attn_g + L * 256, attn_beta + L * 256, ph, pl, ph, pl);
    }

    // 5) player layers
    for (int L = 0; L < 2; ++L)
        gemm_cs_kernel<true, true, 1><<<512, 256, 0, stream>>>(
            ph, pl, player_wp + (size_t)L * 65536,
            player_wp + 131072 + (size_t)L * 65536, player_b + L * 256,
            player_g + L * 256, player_bt + L * 256, ph, pl, ph, pl);

    // 6) masked segment-sum -> teams0 fp32 [512][512]
    team_reduce_kernel<<<512, 256, 0, stream>>>(x, ph, pl, teams0);

    // 7) team layers (ping-pong)
    tail_gemm<512, 512, true><<<32, 256, 0, stream>>>(
        teams0, team_wp, team_wp + 524288, team_b,
        team_g, team_beta, teams0, teams1);
    tail_gemm<512, 512, true><<<32, 256, 0, stream>>>(
        teams1, team_wp + 262144, team_wp + 524288 + 262144, team_b + 512,
        team_g + 512, team_beta + 512, teams1, teams0);

    // 8) pre (512->256) + lnf + pred
    tail_gemm<512, 256, false><<<32, 256, 0, stream>>>(
        teams0, pre_wp, pre_wp + 131072, pre_b, pre_g, pre_beta,
        nullptr, o5);
    ln_kernel<<<512, 64, 0, stream>>>(o5, lnf_g, lnf_b, o5);
    pred_kernel<<<512, 64, 0, stream>>>(o5, pred_w, pred_b, (float*)d_out);
}

// Round 12
// 750.077 us; speedup vs baseline: 1.2046x; 1.1030x over previous
//
#include <hip/hip_runtime.h>
#include <math.h>

// SimplePlayerModel on MI355X — Round 12.
// R10/R11 verdict: R9's row-split LDS-W GEMM is the local optimum; col-split
// variants all regress. R12 = R9 verbatim + row-local epilogue fusion:
//  - player2's epilogue computes the masked team segment-sum directly
//    (block b owns exactly batch b's 64 player rows) -> team_reduce launch,
//    player2 stream write, and team_reduce re-read all eliminated.
//  - pre+lnf+pred fused into one tail kernel (2 extra LDS reduce rounds).
// Launches 17 -> 14. Numerics unchanged (team sum now from fp32, better).

typedef __bf16 bf16x8 __attribute__((ext_vector_type(8)));
typedef __bf16 bf16x4 __attribute__((ext_vector_type(4)));
typedef __bf16 bf16x2 __attribute__((ext_vector_type(2)));
typedef float  f32x4  __attribute__((ext_vector_type(4)));
typedef unsigned short u16;
typedef unsigned short u16x8 __attribute__((ext_vector_type(8)));

__device__ __forceinline__ u16 f2b(float f) {            // fp32 -> bf16 RNE
    unsigned int u = __builtin_bit_cast(unsigned int, f);
    return (u16)((u + 0x7fffu + ((u >> 16) & 1u)) >> 16);
}
__device__ __forceinline__ float b2f(u16 u) {
    unsigned int v = ((unsigned int)u) << 16;
    return __builtin_bit_cast(float, v);
}
__device__ __forceinline__ bf16x8 ld2x64(const u16* p) { // two 8B LDS loads
    bf16x4 lo = *(const bf16x4*)p;
    bf16x4 hi = *(const bf16x4*)(p + 4);
    return __builtin_shufflevector(lo, hi, 0, 1, 2, 3, 4, 5, 6, 7);
}
__device__ __forceinline__ bf16x8 ld4x32(const u16* p) { // four 4B LDS loads
    bf16x2 a = *(const bf16x2*)p,     b = *(const bf16x2*)(p + 2);
    bf16x2 c = *(const bf16x2*)(p + 4), d = *(const bf16x2*)(p + 6);
    bf16x4 lo = __builtin_shufflevector(a, b, 0, 1, 2, 3);
    bf16x4 hi = __builtin_shufflevector(c, d, 0, 1, 2, 3);
    return __builtin_shufflevector(lo, hi, 0, 1, 2, 3, 4, 5, 6, 7);
}
__device__ __forceinline__ void split8(const float* __restrict__ s,
                                       bf16x8& hi, bf16x8& lo) {
    u16x8 h, l;
    #pragma unroll
    for (int j = 0; j < 8; ++j) {
        float v  = s[j];
        u16  hb  = f2b(v);
        h[j] = hb;
        l[j] = f2b(v - b2f(hb));
    }
    hi = __builtin_bit_cast(bf16x8, h);
    lo = __builtin_bit_cast(bf16x8, l);
}

// --------------------------------------------- LDS-staged bf16x3 MFMA GEMM
// (R9 row-split body.) Block = 256 thr, 64 rows (4 waves x 16 rows),
// OUT=256 cols. W (hi+lo) double-buffered in LDS, one barrier/kt, A ring-3.
// TEAM: epilogue computes masked team segment-sum instead of storing Y
// (block b == batch b's 64 player rows); tsum scratch aliased onto Wb.
template<int IN, bool LN, bool RES, bool AF32, int OMODE, bool TEAM>
__device__ __forceinline__
void gemm_body(const void* __restrict__ Xa, const void* __restrict__ Xb, int ldX,
               const u16* __restrict__ Whi, const u16* __restrict__ Wlo,
               const float* __restrict__ bias,
               const float* __restrict__ g, const float* __restrict__ beta,
               const u16* __restrict__ resh, const u16* __restrict__ resl,
               int ldRes, void* __restrict__ Y0, void* __restrict__ Y1, int ldY,
               const float* __restrict__ xmask, float* __restrict__ teams,
               u16* __restrict__ Wb)
{
    constexpr int KT = IN / 32;
    const int tid = threadIdx.x;
    const int wv = tid >> 6, lane = tid & 63;
    const int quad = lane >> 4, l16 = lane & 15;
    const long arow = (long)blockIdx.x * 64 + wv * 16 + l16;

    const u16* sbase[8];
    int sdst[8];
    #pragma unroll
    for (int i = 0; i < 8; ++i) {
        int cid = tid + i * 256;
        int plane = cid >> 10, nt = (cid >> 6) & 15, slot = cid & 63;
        int q = slot >> 4, c = slot & 15;
        sbase[i] = (plane ? Wlo : Whi) + (long)(nt * 16 + c) * IN + q * 8;
        sdst[i]  = (plane * 16 + nt) * 512 + slot * 8;
    }
    u16x8 wreg[8];
    auto issueW = [&](int kt) {
        #pragma unroll
        for (int i = 0; i < 8; ++i) wreg[i] = *(const u16x8*)(sbase[i] + kt * 32);
    };
    auto commitW = [&](int buf) {
        #pragma unroll
        for (int i = 0; i < 8; ++i)
            *(u16x8*)&Wb[buf * 16384 + sdst[i]] = wreg[i];
    };

    bf16x8 ah[3], al[3];
    auto loadA = [&](int kt) {
        int s = kt % 3;
        long aofs = arow * (long)ldX + kt * 32 + quad * 8;
        if constexpr (AF32) {
            float av[8];
            *(f32x4*)&av[0] = *(const f32x4*)&((const float*)Xa)[aofs];
            *(f32x4*)&av[4] = *(const f32x4*)&((const float*)Xa)[aofs + 4];
            split8(av, ah[s], al[s]);
        } else {
            ah[s] = *(const bf16x8*)&((const u16*)Xa)[aofs];
            al[s] = *(const bf16x8*)&((const u16*)Xb)[aofs];
        }
    };

    f32x4 acc[16];
    #pragma unroll
    for (int nt = 0; nt < 16; ++nt) acc[nt] = f32x4{0.f, 0.f, 0.f, 0.f};

    issueW(0);
    commitW(0);
    if (KT > 1) issueW(1);
    loadA(0);
    if (KT > 1) loadA(1);
    __syncthreads();

    #pragma unroll
    for (int kt = 0; kt < KT; ++kt) {
        if (kt + 2 < KT) loadA(kt + 2);
        const u16* wb = Wb + (kt & 1) * 16384;
        const int s = kt % 3;
        #pragma unroll
        for (int nt = 0; nt < 16; ++nt) {
            bf16x8 bhi = *(const bf16x8*)&wb[nt * 512 + lane * 8];
            bf16x8 blo = *(const bf16x8*)&wb[(16 + nt) * 512 + lane * 8];
            acc[nt] = __builtin_amdgcn_mfma_f32_16x16x32_bf16(al[s], bhi, acc[nt], 0, 0, 0);
            acc[nt] = __builtin_amdgcn_mfma_f32_16x16x32_bf16(ah[s], blo, acc[nt], 0, 0, 0);
            acc[nt] = __builtin_amdgcn_mfma_f32_16x16x32_bf16(ah[s], bhi, acc[nt], 0, 0, 0);
        }
        if (kt + 1 < KT) {
            commitW((kt + 1) & 1);
            if (kt + 2 < KT) issueW(kt + 2);
            __syncthreads();
        }
    }

    #pragma unroll
    for (int nt = 0; nt < 16; ++nt) {
        float bc = bias[nt * 16 + l16];
        #pragma unroll
        for (int r = 0; r < 4; ++r) acc[nt][r] += bc;
    }

    float mean[4], rstd[4];
    if constexpr (LN) {
        float s1[4] = {0, 0, 0, 0}, s2[4] = {0, 0, 0, 0};
        #pragma unroll
        for (int nt = 0; nt < 16; ++nt)
            #pragma unroll
            for (int r = 0; r < 4; ++r) {
                s1[r] += acc[nt][r];
                s2[r] += acc[nt][r] * acc[nt][r];
            }
        #pragma unroll
        for (int off = 1; off < 16; off <<= 1)
            #pragma unroll
            for (int r = 0; r < 4; ++r) {
                s1[r] += __shfl_xor(s1[r], off, 64);
                s2[r] += __shfl_xor(s2[r], off, 64);
            }
        #pragma unroll
        for (int r = 0; r < 4; ++r) {
            mean[r] = s1[r] * (1.0f / 256.f);
            float var = s2[r] * (1.0f / 256.f) - mean[r] * mean[r];
            rstd[r] = rsqrtf(var + 1e-5f);
        }
    }

    if constexpr (TEAM) {
        // masked team segment-sum over this block's 64 rows (batch b = blk)
        float m[4];
        #pragma unroll
        for (int r = 0; r < 4; ++r) {
            long row = (long)blockIdx.x * 64 + wv * 16 + quad * 4 + r;
            m[r] = (xmask[row * 64 + 63] == 1.0f) ? 1.0f : 0.0f;
        }
        float ts[16];
        #pragma unroll
        for (int nt = 0; nt < 16; ++nt) {
            int col = nt * 16 + l16;
            float gc = g[col], bc2 = beta[col];
            ts[nt] = 0.f;
            #pragma unroll
            for (int r = 0; r < 4; ++r) {
                long row = (long)blockIdx.x * 64 + wv * 16 + quad * 4 + r;
                float v = (acc[nt][r] - mean[r]) * rstd[r] * gc + bc2;
                v += b2f(resh[row * ldRes + col]) + b2f(resl[row * ldRes + col]);
                ts[nt] += m[r] * v;
            }
        }
        // reduce across quads (rows of this wave)
        #pragma unroll
        for (int nt = 0; nt < 16; ++nt) {
            ts[nt] += __shfl_xor(ts[nt], 16, 64);
            ts[nt] += __shfl_xor(ts[nt], 32, 64);
        }
        __syncthreads();                       // all Wb reads done
        float* tsum = (float*)Wb;              // alias: 4 x 256 floats
        if (quad == 0) {
            #pragma unroll
            for (int nt = 0; nt < 16; ++nt)
                tsum[wv * 256 + nt * 16 + l16] = ts[nt];
        }
        __syncthreads();
        if (tid < 256) {
            float tot = tsum[tid] + tsum[256 + tid]
                      + tsum[512 + tid] + tsum[768 + tid];
            teams[(long)blockIdx.x * 512 + tid]       = tot;
            teams[(long)blockIdx.x * 512 + 256 + tid] = tot;
        }
        return;
    }

    #pragma unroll
    for (int nt = 0; nt < 16; ++nt) {
        int col = nt * 16 + l16;
        float gc = 1.f, bc2 = 0.f;
        if constexpr (LN) { gc = g[col]; bc2 = beta[col]; }
        #pragma unroll
        for (int r = 0; r < 4; ++r) {
            long row = (long)blockIdx.x * 64 + wv * 16 + quad * 4 + r;
            float v = acc[nt][r];
            if constexpr (LN) v = (v - mean[r]) * rstd[r] * gc + bc2;
            if constexpr (RES)
                v += b2f(resh[row * ldRes + col]) + b2f(resl[row * ldRes + col]);
            long yofs = row * ldY + col;
            if constexpr (OMODE == 0) {
                ((float*)Y0)[yofs] = v;
            } else if constexpr (OMODE == 1) {
                u16 hb = f2b(v);
                ((u16*)Y0)[yofs] = hb;
                ((u16*)Y1)[yofs] = f2b(v - b2f(hb));
            } else {
                ((u16*)Y0)[yofs] = f2b(v);
            }
        }
    }
}

template<int IN, bool LN, bool RES, bool AF32, int OMODE, bool TEAM>
__global__ __launch_bounds__(256)
void gemm_kernel(const void* __restrict__ Xa, const void* __restrict__ Xb, int ldX,
                 const u16* __restrict__ Whi, const u16* __restrict__ Wlo,
                 const float* __restrict__ bias,
                 const float* __restrict__ g, const float* __restrict__ beta,
                 const u16* __restrict__ resh, const u16* __restrict__ resl,
                 int ldRes, void* __restrict__ Y0, void* __restrict__ Y1, int ldY,
                 const float* __restrict__ xmask, float* __restrict__ teams)
{
    __shared__ u16 Wb[32768];
    gemm_body<IN, LN, RES, AF32, OMODE, TEAM>(Xa, Xb, ldX, Whi, Wlo, bias, g,
                                              beta, resh, resl, ldRes, Y0, Y1,
                                              ldY, xmask, teams, Wb);
}

// qkv projections: grid.y = wsel in {0,1,2}; plain-bf16 token-major out.
__global__ __launch_bounds__(256)
void qkv_proj(const u16* __restrict__ ph, const u16* __restrict__ pl,
              const u16* __restrict__ cwL, const float* __restrict__ cb,
              u16* __restrict__ qb, u16* __restrict__ kb, u16* __restrict__ vh)
{
    __shared__ u16 Wb[32768];
    int wsel = blockIdx.y;
    const u16* whi = cwL + (long)wsel * 65536;
    const u16* wlo = cwL + 393216 + (long)wsel * 65536;
    u16* Y = (wsel == 0) ? qb : (wsel == 1) ? kb : vh;
    gemm_body<256, false, false, false, 2, false>(
        ph, pl, 256, whi, wlo, cb + wsel * 256, nullptr, nullptr,
        nullptr, nullptr, 0, Y, nullptr, 256, nullptr, nullptr, Wb);
}

// ----------------------------------------------- combined in_proj @ qkv_proj
__global__ __launch_bounds__(256)
void combine_kernel(const float* __restrict__ inw, const float* __restrict__ inb,
                    const float* __restrict__ qw, const float* __restrict__ kw,
                    const float* __restrict__ vw, const float* __restrict__ qb,
                    const float* __restrict__ kb, const float* __restrict__ vb,
                    u16* __restrict__ cw, float* __restrict__ cb)
{
    int idx = blockIdx.y, L = idx / 3, wsel = idx % 3;
    const float* Wa = inw + (long)L * 768 * 256 + wsel * 65536;
    const float* ba = inb + L * 768 + wsel * 256;
    const float* Wf = (wsel == 0 ? qw : wsel == 1 ? kw : vw) + (long)L * 65536;
    const float* bf = (wsel == 0 ? qb : wsel == 1 ? kb : vb) + L * 256;

    int o = blockIdx.x, j = threadIdx.x;
    float s = 0.f;
    for (int mm = 0; mm < 256; ++mm)
        s += Wa[o * 256 + mm] * Wf[mm * 256 + j];
    u16 hb = f2b(s);
    cw[(long)idx * 65536 + o * 256 + j] = hb;
    cw[393216 + (long)idx * 65536 + o * 256 + j] = f2b(s - b2f(hb));

    __shared__ float red[256];
    red[j] = Wa[o * 256 + j] * bf[j];
    __syncthreads();
    for (int st = 128; st > 0; st >>= 1) {
        if (j < st) red[j] += red[j + st];
        __syncthreads();
    }
    if (j == 0) cb[idx * 256 + o] = red[0] + ba[o];
}

// ------------------------------------------- fp32 -> hi/lo bf16 weight planes
__global__ __launch_bounds__(256)
void cast_split_multi(const float* s0, u16* d0, int n0,
                      const float* s1, u16* d1, int n1,
                      const float* s2, u16* d2, int n2,
                      const float* s3, u16* d3, int n3,
                      const float* s4, u16* d4, int n4,
                      const float* s5, u16* d5, int n5)
{
    const float* s; u16* d; int n;
    switch (blockIdx.y) {
        case 0: s = s0; d = d0; n = n0; break;
        case 1: s = s1; d = d1; n = n1; break;
        case 2: s = s2; d = d2; n = n2; break;
        case 3: s = s3; d = d3; n = n3; break;
        case 4: s = s4; d = d4; n = n4; break;
        default: s = s5; d = d5; n = n5; break;
    }
    int i = (blockIdx.x * 256 + threadIdx.x) * 4;
    if (i >= n) return;
    float4 v = *(const float4*)&s[i];
    ushort4 h, l;
    h.x = f2b(v.x); l.x = f2b(v.x - b2f(h.x));
    h.y = f2b(v.y); l.y = f2b(v.y - b2f(h.y));
    h.z = f2b(v.z); l.z = f2b(v.z - b2f(h.z));
    h.w = f2b(v.w); l.w = f2b(v.w - b2f(h.w));
    *(ushort4*)&d[i] = h;
    *(ushort4*)&d[n + i] = l;
}

// ------------------------------------------------------- MFMA flash attention
// (unchanged from R9)
#define VTS 66
#define PS  68
#define EXP2SCALE 0.18033688089184986f   // 0.125 * log2(e)

__global__ __launch_bounds__(256)
void attn_kernel(const u16* __restrict__ qbuf, const u16* __restrict__ kbuf,
                 const u16* __restrict__ vh,
                 u16* __restrict__ ofh, u16* __restrict__ ofl)
{
    const int n = blockIdx.x, h = blockIdx.y, sq = blockIdx.z;
    const int tid = threadIdx.x;
    const int wv = tid >> 6, lane = tid & 63;
    const int quad = lane >> 4, l16 = lane & 15;

    __shared__ u16 Vth[64 * VTS];
    __shared__ u16 Pbh[4][32 * PS];

    bf16x8 qf[2][2];
    #pragma unroll
    for (int rt = 0; rt < 2; ++rt)
        #pragma unroll
        for (int kc = 0; kc < 2; ++kc) {
            long s = sq * 128 + wv * 32 + rt * 16 + l16;
            qf[rt][kc] = *(const bf16x8*)&qbuf[(s * 64 + n) * 256 + h * 64
                                               + kc * 32 + quad * 8];
        }

    f32x4 o[2][4];
    #pragma unroll
    for (int rt = 0; rt < 2; ++rt)
        #pragma unroll
        for (int dt = 0; dt < 4; ++dt) o[rt][dt] = f32x4{0.f, 0.f, 0.f, 0.f};
    float l_run[2][4] = {{0.f, 0.f, 0.f, 0.f}, {0.f, 0.f, 0.f, 0.f}};

    for (int tb = 0; tb < 8; ++tb) {
        __syncthreads();
        for (int i = tid; i < 512; i += 256) {
            int t = i >> 3, c = i & 7;
            u16x8 hvv = *(const u16x8*)&vh[((long)(tb * 64 + t) * 64 + n) * 256
                                           + h * 64 + c * 8];
            #pragma unroll
            for (int j = 0; j < 8; ++j)
                Vth[(c * 8 + j) * VTS + t] = hvv[j];
        }
        __syncthreads();

        f32x4 sA[2][4];
        #pragma unroll
        for (int rt = 0; rt < 2; ++rt)
            #pragma unroll
            for (int tt = 0; tt < 4; ++tt) sA[rt][tt] = f32x4{0.f, 0.f, 0.f, 0.f};
        #pragma unroll
        for (int kc = 0; kc < 2; ++kc)
            #pragma unroll
            for (int tt = 0; tt < 4; ++tt) {
                bf16x8 kf = *(const bf16x8*)
                    &kbuf[((long)(tb * 64 + tt * 16 + l16) * 64 + n) * 256
                          + h * 64 + kc * 32 + quad * 8];
                sA[0][tt] = __builtin_amdgcn_mfma_f32_16x16x32_bf16(
                    qf[0][kc], kf, sA[0][tt], 0, 0, 0);
                sA[1][tt] = __builtin_amdgcn_mfma_f32_16x16x32_bf16(
                    qf[1][kc], kf, sA[1][tt], 0, 0, 0);
            }

        #pragma unroll
        for (int rt = 0; rt < 2; ++rt)
            #pragma unroll
            for (int r = 0; r < 4; ++r) {
                float p0 = exp2f(sA[rt][0][r] * EXP2SCALE);
                float p1 = exp2f(sA[rt][1][r] * EXP2SCALE);
                float p2 = exp2f(sA[rt][2][r] * EXP2SCALE);
                float p3 = exp2f(sA[rt][3][r] * EXP2SCALE);
                int prow = (rt * 16 + quad * 4 + r) * PS + l16;
                Pbh[wv][prow +  0] = f2b(p0);
                Pbh[wv][prow + 16] = f2b(p1);
                Pbh[wv][prow + 32] = f2b(p2);
                Pbh[wv][prow + 48] = f2b(p3);
                l_run[rt][r] += (p0 + p1) + (p2 + p3);
            }

        #pragma unroll
        for (int kc = 0; kc < 2; ++kc) {
            bf16x8 pfh[2];
            #pragma unroll
            for (int rt = 0; rt < 2; ++rt)
                pfh[rt] = ld2x64(&Pbh[wv][(rt * 16 + l16) * PS
                                          + kc * 32 + quad * 8]);
            #pragma unroll
            for (int dt = 0; dt < 4; ++dt) {
                bf16x8 vfh = ld4x32(&Vth[(dt * 16 + l16) * VTS
                                         + kc * 32 + quad * 8]);
                o[0][dt] = __builtin_amdgcn_mfma_f32_16x16x32_bf16(
                    pfh[0], vfh, o[0][dt], 0, 0, 0);
                o[1][dt] = __builtin_amdgcn_mfma_f32_16x16x32_bf16(
                    pfh[1], vfh, o[1][dt], 0, 0, 0);
            }
        }
    }

    #pragma unroll
    for (int off = 1; off < 16; off <<= 1)
        #pragma unroll
        for (int rt = 0; rt < 2; ++rt)
            #pragma unroll
            for (int r = 0; r < 4; ++r)
                l_run[rt][r] += __shfl_xor(l_run[rt][r], off, 64);

    #pragma unroll
    for (int rt = 0; rt < 2; ++rt)
        #pragma unroll
        for (int r = 0; r < 4; ++r) {
            float inv = 1.0f / l_run[rt][r];
            long s = sq * 128 + wv * 32 + rt * 16 + quad * 4 + r;
            #pragma unroll
            for (int dt = 0; dt < 4; ++dt) {
                long idx = (s * 64 + n) * 256 + h * 64 + dt * 16 + l16;
                float val = o[rt][dt][r] * inv;
                u16 hb = f2b(val);
                ofh[idx] = hb;
                ofl[idx] = f2b(val - b2f(hb));
            }
        }
}

// ---------------------------------------- tail GEMM (512-row team layers)
template<int IN, int OUT, bool RES>
__global__ __launch_bounds__(256)
void tail_gemm(const float* __restrict__ X,
               const u16* __restrict__ Whi, const u16* __restrict__ Wlo,
               const float* __restrict__ bias,
               const float* __restrict__ g, const float* __restrict__ beta,
               const float* __restrict__ res, float* __restrict__ Y)
{
    constexpr int NTW = OUT / 64;
    constexpr int KT  = IN / 32;
    const int tid = threadIdx.x;
    const int wv = tid >> 6, lane = tid & 63;
    const int quad = lane >> 4, l16 = lane & 15;
    const int row0 = blockIdx.x * 16;
    const int colbase = wv * (OUT / 4);

    f32x4 acc[NTW];
    #pragma unroll
    for (int nt = 0; nt < NTW; ++nt) acc[nt] = f32x4{0.f, 0.f, 0.f, 0.f};

    #pragma unroll
    for (int kt = 0; kt < KT; ++kt) {
        float av[8];
        long aofs = (long)(row0 + l16) * IN + kt * 32 + quad * 8;
        *(f32x4*)&av[0] = *(const f32x4*)&X[aofs];
        *(f32x4*)&av[4] = *(const f32x4*)&X[aofs + 4];
        bf16x8 ah, al;
        split8(av, ah, al);
        #pragma unroll
        for (int nt = 0; nt < NTW; ++nt) {
            long wofs = (long)(colbase + nt * 16 + l16) * IN + kt * 32 + quad * 8;
            bf16x8 bhi = *(const bf16x8*)&Whi[wofs];
            bf16x8 blo = *(const bf16x8*)&Wlo[wofs];
            acc[nt] = __builtin_amdgcn_mfma_f32_16x16x32_bf16(al, bhi, acc[nt], 0, 0, 0);
            acc[nt] = __builtin_amdgcn_mfma_f32_16x16x32_bf16(ah, blo, acc[nt], 0, 0, 0);
            acc[nt] = __builtin_amdgcn_mfma_f32_16x16x32_bf16(ah, bhi, acc[nt], 0, 0, 0);
        }
    }

    #pragma unroll
    for (int nt = 0; nt < NTW; ++nt) {
        float bc = bias[colbase + nt * 16 + l16];
        #pragma unroll
        for (int r = 0; r < 4; ++r) acc[nt][r] += bc;
    }

    float s1[4] = {0, 0, 0, 0}, s2[4] = {0, 0, 0, 0};
    #pragma unroll
    for (int nt = 0; nt < NTW; ++nt)
        #pragma unroll
        for (int r = 0; r < 4; ++r) {
            s1[r] += acc[nt][r];
            s2[r] += acc[nt][r] * acc[nt][r];
        }
    #pragma unroll
    for (int off = 1; off < 16; off <<= 1)
        #pragma unroll
        for (int r = 0; r < 4; ++r) {
            s1[r] += __shfl_xor(s1[r], off, 64);
            s2[r] += __shfl_xor(s2[r], off, 64);
        }
    __shared__ float r1[64], r2[64];
    if (l16 == 0) {
        #pragma unroll
        for (int r = 0; r < 4; ++r) {
            r1[wv * 16 + quad * 4 + r] = s1[r];
            r2[wv * 16 + quad * 4 + r] = s2[r];
        }
    }
    __syncthreads();
    float mean[4], rstd[4];
    #pragma unroll
    for (int r = 0; r < 4; ++r) {
        int rr = quad * 4 + r;
        float t1 = r1[rr] + r1[16 + rr] + r1[32 + rr] + r1[48 + rr];
        float t2 = r2[rr] + r2[16 + rr] + r2[32 + rr] + r2[48 + rr];
        mean[r] = t1 * (1.0f / OUT);
        float var = t2 * (1.0f / OUT) - mean[r] * mean[r];
        rstd[r] = rsqrtf(var + 1e-5f);
    }
    #pragma unroll
    for (int nt = 0; nt < NTW; ++nt) {
        int col = colbase + nt * 16 + l16;
        float gc = g[col], bc2 = beta[col];
        #pragma unroll
        for (int r = 0; r < 4; ++r) {
            int row = row0 + quad * 4 + r;
            float v = (acc[nt][r] - mean[r]) * rstd[r] * gc + bc2;
            if constexpr (RES) v += res[(long)row * OUT + col];
            Y[(long)row * OUT + col] = v;
        }
    }
}

// --------------------- fused pre (512->256) + lnf + pred -> out[512] fp32
__global__ __launch_bounds__(256)
void tail_pred(const float* __restrict__ X,
               const u16* __restrict__ Whi, const u16* __restrict__ Wlo,
               const float* __restrict__ bias,
               const float* __restrict__ g, const float* __restrict__ beta,
               const float* __restrict__ lnf_g, const float* __restrict__ lnf_b,
               const float* __restrict__ pw, const float* __restrict__ pb,
               float* __restrict__ out)
{
    constexpr int IN = 512, OUT = 256, NTW = 4, KT = 16;
    const int tid = threadIdx.x;
    const int wv = tid >> 6, lane = tid & 63;
    const int quad = lane >> 4, l16 = lane & 15;
    const int row0 = blockIdx.x * 16;
    const int colbase = wv * 64;

    f32x4 acc[NTW];
    #pragma unroll
    for (int nt = 0; nt < NTW; ++nt) acc[nt] = f32x4{0.f, 0.f, 0.f, 0.f};

    #pragma unroll
    for (int kt = 0; kt < KT; ++kt) {
        float av[8];
        long aofs = (long)(row0 + l16) * IN + kt * 32 + quad * 8;
        *(f32x4*)&av[0] = *(const f32x4*)&X[aofs];
        *(f32x4*)&av[4] = *(const f32x4*)&X[aofs + 4];
        bf16x8 ah, al;
        split8(av, ah, al);
        #pragma unroll
        for (int nt = 0; nt < NTW; ++nt) {
            long wofs = (long)(colbase + nt * 16 + l16) * IN + kt * 32 + quad * 8;
            bf16x8 bhi = *(const bf16x8*)&Whi[wofs];
            bf16x8 blo = *(const bf16x8*)&Wlo[wofs];
            acc[nt] = __builtin_amdgcn_mfma_f32_16x16x32_bf16(al, bhi, acc[nt], 0, 0, 0);
            acc[nt] = __builtin_amdgcn_mfma_f32_16x16x32_bf16(ah, blo, acc[nt], 0, 0, 0);
            acc[nt] = __builtin_amdgcn_mfma_f32_16x16x32_bf16(ah, bhi, acc[nt], 0, 0, 0);
        }
    }
    #pragma unroll
    for (int nt = 0; nt < NTW; ++nt) {
        float bc = bias[colbase + nt * 16 + l16];
        #pragma unroll
        for (int r = 0; r < 4; ++r) acc[nt][r] += bc;
    }

    __shared__ float r1[64], r2[64];
    // ---- LN 1 (pre_g/pre_beta)
    float s1[4] = {0, 0, 0, 0}, s2[4] = {0, 0, 0, 0};
    #pragma unroll
    for (int nt = 0; nt < NTW; ++nt)
        #pragma unroll
        for (int r = 0; r < 4; ++r) {
            s1[r] += acc[nt][r];
            s2[r] += acc[nt][r] * acc[nt][r];
        }
    #pragma unroll
    for (int off = 1; off < 16; off <<= 1)
        #pragma unroll
        for (int r = 0; r < 4; ++r) {
            s1[r] += __shfl_xor(s1[r], off, 64);
            s2[r] += __shfl_xor(s2[r], off, 64);
        }
    if (l16 == 0)
        #pragma unroll
        for (int r = 0; r < 4; ++r) {
            r1[wv * 16 + quad * 4 + r] = s1[r];
            r2[wv * 16 + quad * 4 + r] = s2[r];
        }
    __syncthreads();
    float vv[NTW][4];
    #pragma unroll
    for (int r = 0; r < 4; ++r) {
        int rr = quad * 4 + r;
        float t1 = r1[rr] + r1[16 + rr] + r1[32 + rr] + r1[48 + rr];
        float t2 = r2[rr] + r2[16 + rr] + r2[32 + rr] + r2[48 + rr];
        float mean = t1 * (1.0f / OUT);
        float rstd = rsqrtf(t2 * (1.0f / OUT) - mean * mean + 1e-5f);
        #pragma unroll
        for (int nt = 0; nt < NTW; ++nt) {
            int col = colbase + nt * 16 + l16;
            vv[nt][r] = (acc[nt][r] - mean) * rstd * g[col] + beta[col];
        }
    }
    // ---- LN 2 (lnf)
    float u1[4] = {0, 0, 0, 0}, u2[4] = {0, 0, 0, 0};
    #pragma unroll
    for (int nt = 0; nt < NTW; ++nt)
        #pragma unroll
        for (int r = 0; r < 4; ++r) {
            u1[r] += vv[nt][r];
            u2[r] += vv[nt][r] * vv[nt][r];
        }
    #pragma unroll
    for (int off = 1; off < 16; off <<= 1)
        #pragma unroll
        for (int r = 0; r < 4; ++r) {
            u1[r] += __shfl_xor(u1[r], off, 64);
            u2[r] += __shfl_xor(u2[r], off, 64);
        }
    __syncthreads();
    if (l16 == 0)
        #pragma unroll
        for (int r = 0; r < 4; ++r) {
            r1[wv * 16 + quad * 4 + r] = u1[r];
            r2[wv * 16 + quad * 4 + r] = u2[r];
        }
    __syncthreads();
    // ---- pred dot
    float pd[4];
    #pragma unroll
    for (int r = 0; r < 4; ++r) {
        int rr = quad * 4 + r;
        float t1 = r1[rr] + r1[16 + rr] + r1[32 + rr] + r1[48 + rr];
        float t2 = r2[rr] + r2[16 + rr] + r2[32 + rr] + r2[48 + rr];
        float mean = t1 * (1.0f / OUT);
        float rstd = rsqrtf(t2 * (1.0f / OUT) - mean * mean + 1e-5f);
        pd[r] = 0.f;
        #pragma unroll
        for (int nt = 0; nt < NTW; ++nt) {
            int col = colbase + nt * 16 + l16;
            float v2 = (vv[nt][r] - mean) * rstd * lnf_g[col] + lnf_b[col];
            pd[r] += v2 * pw[col];
        }
    }
    #pragma unroll
    for (int off = 1; off < 16; off <<= 1)
        #pragma unroll
        for (int r = 0; r < 4; ++r)
            pd[r] += __shfl_xor(pd[r], off, 64);
    __syncthreads();
    if (l16 == 0)
        #pragma unroll
        for (int r = 0; r < 4; ++r)
            r1[wv * 16 + quad * 4 + r] = pd[r];
    __syncthreads();
    if (wv == 0 && l16 == 0) {
        #pragma unroll
        for (int r = 0; r < 4; ++r) {
            int rr = quad * 4 + r;
            out[row0 + rr] = r1[rr] + r1[16 + rr] + r1[32 + rr] + r1[48 + rr]
                           + pb[0];
        }
    }
}

// =========================================================================
extern "C" void kernel_launch(void* const* d_in, const int* in_sizes, int n_in,
                              void* d_out, int out_size, void* d_ws, size_t ws_size,
                              hipStream_t stream)
{
    const float* x         = (const float*)d_in[0];
    const float* emb_w     = (const float*)d_in[1];
    const float* emb_b     = (const float*)d_in[2];
    const float* emb_g     = (const float*)d_in[3];
    const float* emb_beta  = (const float*)d_in[4];
    const float* post_w    = (const float*)d_in[5];
    const float* post_b    = (const float*)d_in[6];
    const float* post_g    = (const float*)d_in[7];
    const float* post_beta = (const float*)d_in[8];
    const float* attn_qw   = (const float*)d_in[9];
    const float* attn_qb   = (const float*)d_in[10];
    const float* attn_kw   = (const float*)d_in[11];
    const float* attn_kb   = (const float*)d_in[12];
    const float* attn_vw   = (const float*)d_in[13];
    const float* attn_vb   = (const float*)d_in[14];
    const float* attn_inw  = (const float*)d_in[15];
    const float* attn_inb  = (const float*)d_in[16];
    const float* attn_outw = (const float*)d_in[17];
    const float* attn_outb = (const float*)d_in[18];
    const float* attn_g    = (const float*)d_in[19];
    const float* attn_beta = (const float*)d_in[20];
    const float* player_w  = (const float*)d_in[21];
    const float* player_b  = (const float*)d_in[22];
    const float* player_g  = (const float*)d_in[23];
    const float* player_bt = (const float*)d_in[24];
    const float* team_w    = (const float*)d_in[25];
    const float* team_b    = (const float*)d_in[26];
    const float* team_g    = (const float*)d_in[27];
    const float* team_beta = (const float*)d_in[28];
    const float* pre_w     = (const float*)d_in[29];
    const float* pre_b     = (const float*)d_in[30];
    const float* pre_g     = (const float*)d_in[31];
    const float* pre_beta  = (const float*)d_in[32];
    const float* lnf_g     = (const float*)d_in[33];
    const float* lnf_b     = (const float*)d_in[34];
    const float* pred_w    = (const float*)d_in[35];
    const float* pred_b    = (const float*)d_in[36];

    // ---- workspace layout
    char* base = (char*)d_ws;
    const size_t NR = (size_t)32768 * 256;
    u16* ph  = (u16*)base;  base += NR * 2;
    u16* pl  = (u16*)base;  base += NR * 2;
    u16* ofh = (u16*)base;  base += NR * 2;
    u16* ofl = (u16*)base;  base += NR * 2;
    u16* vh  = (u16*)base;  base += NR * 2;
    u16* qb  = (u16*)base;  base += NR * 2;
    u16* kb  = (u16*)base;  base += NR * 2;
    float* teams0 = (float*)base; base += (size_t)512 * 512 * 4;
    float* teams1 = (float*)base; base += (size_t)512 * 512 * 4;
    u16* emb_wp    = (u16*)base;  base += (size_t)2 * 16384 * 2;
    u16* post_wp   = (u16*)base;  base += (size_t)2 * 65536 * 2;
    u16* outw_p    = (u16*)base;  base += (size_t)2 * 131072 * 2;
    u16* player_wp = (u16*)base;  base += (size_t)2 * 131072 * 2;
    u16* team_wp   = (u16*)base;  base += (size_t)2 * 524288 * 2;
    u16* pre_wp    = (u16*)base;  base += (size_t)2 * 131072 * 2;
    u16* cwb       = (u16*)base;  base += (size_t)2 * 393216 * 2;
    float* cbf     = (float*)base; base += (size_t)1536 * 4;

    // 1) weights -> hi/lo bf16 planes
    cast_split_multi<<<dim3(512, 6), 256, 0, stream>>>(
        emb_w, emb_wp, 16384,
        post_w, post_wp, 65536,
        attn_outw, outw_p, 131072,
        player_w, player_wp, 131072,
        team_w, team_wp, 524288,
        pre_w, pre_wp, 131072);

    // 2) combined qkv weights
    combine_kernel<<<dim3(256, 6), 256, 0, stream>>>(
        attn_inw, attn_inb, attn_qw, attn_kw, attn_vw,
        attn_qb, attn_kb, attn_vb, cwb, cbf);

    // 3) embedding + post-embedding
    gemm_kernel<64, true, false, true, 1, false><<<512, 256, 0, stream>>>(
        x, nullptr, 64, emb_wp, emb_wp + 16384, emb_b, emb_g, emb_beta,
        nullptr, nullptr, 0, ph, pl, 256, nullptr, nullptr);
    gemm_kernel<256, true, true, false, 1, false><<<512, 256, 0, stream>>>(
        ph, pl, 256, post_wp, post_wp + 65536, post_b, post_g, post_beta,
        ph, pl, 256, ph, pl, 256, nullptr, nullptr);

    // 4) attention layers
    for (int L = 0; L < 2; ++L) {
        qkv_proj<<<dim3(512, 3), 256, 0, stream>>>(
            ph, pl, cwb + (size_t)L * 3 * 65536, cbf + L * 768, qb, kb, vh);
        attn_kernel<<<dim3(64, 4, 4), 256, 0, stream>>>(qb, kb, vh, ofh, ofl);
        gemm_kernel<256, true, true, false, 1, false><<<512, 256, 0, stream>>>(
            ofh, ofl, 256, outw_p + (size_t)L * 65536,
            outw_p + 131072 + (size_t)L * 65536, attn_outb + L * 256,
            attn_g + L * 256, attn_beta + L * 256, ph, pl, 256, ph, pl, 256,
            nullptr, nullptr);
    }

    // 5) player layer 0 (stream), player layer 1 fused with team reduce
    gemm_kernel<256, true, true, false, 1, false><<<512, 256, 0, stream>>>(
        ph, pl, 256, player_wp, player_wp + 131072, player_b,
        player_g, player_bt, ph, pl, 256, ph, pl, 256, nullptr, nullptr);
    gemm_kernel<256, true, true, false, 1, true><<<512, 256, 0, stream>>>(
        ph, pl, 256, player_wp + 65536, player_wp + 131072 + 65536,
        player_b + 256, player_g + 256, player_bt + 256, ph, pl, 256,
        nullptr, nullptr, 256, x, teams0);

    // 6) team layers (ping-pong)
    tail_gemm<512, 512, true><<<32, 256, 0, stream>>>(
        teams0, team_wp, team_wp + 524288, team_b,
        team_g, team_beta, teams0, teams1);
    tail_gemm<512, 512, true><<<32, 256, 0, stream>>>(
        teams1, team_wp + 262144, team_wp + 524288 + 262144, team_b + 512,
        team_g + 512, team_beta + 512, teams1, teams0);

    // 7) fused pre + lnf + pred
    tail_pred<<<32, 256, 0, stream>>>(
        teams0, pre_wp, pre_wp + 131072, pre_b, pre_g, pre_beta,
        lnf_g, lnf_b, pred_w, pred_b, (float*)d_out);
}